// Round 6
// baseline (217.108 us; speedup 1.0000x reference)
//
#include <hip/hip_runtime.h>
#include <math.h>

#define DIM_IN 128
#define DIM_H 64
#define DIM_OUT 16
#define NBSHIFT 8  // 256 nodes per bucket

typedef __attribute__((ext_vector_type(8))) short bf16x8;
typedef __attribute__((ext_vector_type(4))) float f32x4;

__device__ __forceinline__ ushort f2bf(float f) {
  uint u = __float_as_uint(f);
  return (ushort)((u + 0x7FFF + ((u >> 16) & 1)) >> 16);
}
__device__ __forceinline__ float bf2f(ushort s) {
  return __uint_as_float(((uint)s) << 16);
}
__device__ __forceinline__ uint cvtpk(float lo, float hi) {
  uint r;
  asm("v_cvt_pk_bf16_f32 %0, %1, %2" : "=v"(r) : "v"(lo), "v"(hi));
  return r;
}

// ======================= bucket histogram =======================
__global__ __launch_bounds__(256) void k_bhist(const int* __restrict__ dst, int E,
                                               int NB, int* __restrict__ gbhist) {
  __shared__ int lh[512];
  int t = threadIdx.x;
  lh[t] = 0;
  lh[t + 256] = 0;
  __syncthreads();
  for (int i = blockIdx.x * 256 + t; i < E; i += gridDim.x * 256)
    atomicAdd(&lh[dst[i] >> NBSHIFT], 1);
  __syncthreads();
  for (int b = t; b < NB; b += 256) {
    int c = lh[b];
    if (c) atomicAdd(&gbhist[b], c);
  }
}

// exclusive scan of gbhist[NB] -> bbase, bcursor (NB <= 512), single block
__global__ __launch_bounds__(512) void k_bscan(const int* __restrict__ gbhist, int NB,
                                               int* __restrict__ bbase,
                                               int* __restrict__ bcursor) {
  __shared__ int sb[512];
  int t = threadIdx.x;
  int v = (t < NB) ? gbhist[t] : 0;
  sb[t] = v;
  __syncthreads();
  for (int off = 1; off < 512; off <<= 1) {
    int add = (t >= off) ? sb[t - off] : 0;
    __syncthreads();
    sb[t] += add;
    __syncthreads();
  }
  if (t < NB) {
    int e = sb[t] - v;
    bbase[t] = e;
    bcursor[t] = e;
  }
}

// ======================= partition into bucket regions =======================
__global__ __launch_bounds__(256) void k_part(const int* __restrict__ src,
                                              const int* __restrict__ dst, int E,
                                              int NB, int* __restrict__ bcursor,
                                              int2* __restrict__ pairs) {
  __shared__ int lh[512];
  __shared__ int lcur[512];
  int t = threadIdx.x;
  lh[t] = 0;
  lh[t + 256] = 0;
  __syncthreads();
  int e0 = blockIdx.x * 8192;
  int e1 = min(E, e0 + 8192);
  for (int i = e0 + t; i < e1; i += 256) atomicAdd(&lh[dst[i] >> NBSHIFT], 1);
  __syncthreads();
  for (int b = t; b < NB; b += 256) {
    int c = lh[b];
    lcur[b] = c ? atomicAdd(&bcursor[b], c) : 0;
  }
  __syncthreads();
  for (int i = e0 + t; i < e1; i += 256) {
    int d = dst[i];
    int pos = atomicAdd(&lcur[d >> NBSHIFT], 1);
    pairs[pos] = make_int2(src[i], d);
  }
}

// ======================= per-bucket CSR + deg + dinv + per-node sort ========
// One block per bucket: node histogram + scan in LDS, scatter srcs into LDS,
// per-node insertion sort (ascending src) for gather temporal locality, then
// coalesced write-back.
__global__ __launch_bounds__(256) void k_csr(const int2* __restrict__ pairs,
                                             const int* __restrict__ gbhist,
                                             const int* __restrict__ bbase, int n,
                                             int* __restrict__ degi,
                                             float* __restrict__ dinv,
                                             int* __restrict__ rowptr,
                                             int* __restrict__ srcs) {
  __shared__ int nh[256];
  __shared__ int ncur[256];
  __shared__ int ssrc[8192];
  int t = threadIdx.x;
  int b = blockIdx.x;
  int base = bbase[b];
  int cnt = gbhist[b];
  bool fits = (cnt <= 8192);
  nh[t] = 0;
  __syncthreads();
  for (int i = t; i < cnt; i += 256) atomicAdd(&nh[pairs[base + i].y & 255], 1);
  __syncthreads();
  int node = (b << NBSHIFT) + t;
  int v = nh[t];
  if (node < n) {
    degi[node] = v;
    dinv[node] = rsqrtf((float)v + 1.0f);
  }
  __syncthreads();
  for (int off = 1; off < 256; off <<= 1) {
    int add = (t >= off) ? nh[t - off] : 0;
    __syncthreads();
    nh[t] += add;
    __syncthreads();
  }
  int excl = nh[t] - v;  // bucket-local segment start for node t
  if (node < n) rowptr[node] = base + excl;
  ncur[t] = excl;
  __syncthreads();
  if (fits) {
    for (int i = t; i < cnt; i += 256) {
      int2 p = pairs[base + i];
      int pos = atomicAdd(&ncur[p.y & 255], 1);
      ssrc[pos] = p.x;
    }
    __syncthreads();
    // ascending insertion sort of this thread's node segment
    for (int i = 1; i < v; ++i) {
      int key = ssrc[excl + i];
      int j = i - 1;
      while (j >= 0 && ssrc[excl + j] > key) {
        ssrc[excl + j + 1] = ssrc[excl + j];
        --j;
      }
      ssrc[excl + j + 1] = key;
    }
    __syncthreads();
    for (int i = t; i < cnt; i += 256) srcs[base + i] = ssrc[i];
  } else {
    for (int i = t; i < cnt; i += 256) {
      int2 p = pairs[base + i];
      int pos = atomicAdd(&ncur[p.y & 255], 1);
      srcs[base + pos] = p.x;
    }
  }
}

// ======================= GEMM1 (MFMA bf16): h1 = x @ W1 =======================
__global__ __launch_bounds__(256, 4) void k_gemm1m(const float* __restrict__ x,
                                                   const float* __restrict__ W,
                                                   ushort* __restrict__ h, int n,
                                                   int nTiles) {
  const int t = threadIdx.x;
  const int lane = t & 63;
  const int wid = blockIdx.x * 4 + (t >> 6);
  const int nW = gridDim.x * 4;
  const int cc = lane & 15;        // A row offset / B,D col offset
  const int kb = (lane >> 4) * 8;  // k-octet within 32-chunk

  bf16x8 bfrag[4][4];
#pragma unroll
  for (int kc = 0; kc < 4; ++kc)
#pragma unroll
    for (int nt = 0; nt < 4; ++nt) {
      union { bf16x8 v; uint u[4]; } fb;
#pragma unroll
      for (int j = 0; j < 4; ++j) {
        float lo = W[(size_t)(kc * 32 + kb + 2 * j) * DIM_H + nt * 16 + cc];
        float hi = W[(size_t)(kc * 32 + kb + 2 * j + 1) * DIM_H + nt * 16 + cc];
        fb.u[j] = cvtpk(lo, hi);
      }
      bfrag[kc][nt] = fb.v;
    }

  for (int tile = wid; tile < nTiles; tile += nW) {
    int row0 = tile * 16;
    int ra = row0 + cc;
    if (ra > n - 1) ra = n - 1;
    const float* xp = x + (size_t)ra * DIM_IN;
    f32x4 acc[4] = {{0.f, 0.f, 0.f, 0.f},
                    {0.f, 0.f, 0.f, 0.f},
                    {0.f, 0.f, 0.f, 0.f},
                    {0.f, 0.f, 0.f, 0.f}};
#pragma unroll
    for (int kc = 0; kc < 4; ++kc) {
      float4 a0 = *(const float4*)(xp + kc * 32 + kb);
      float4 a1 = *(const float4*)(xp + kc * 32 + kb + 4);
      union { bf16x8 v; uint u[4]; } fa;
      fa.u[0] = cvtpk(a0.x, a0.y);
      fa.u[1] = cvtpk(a0.z, a0.w);
      fa.u[2] = cvtpk(a1.x, a1.y);
      fa.u[3] = cvtpk(a1.z, a1.w);
#pragma unroll
      for (int nt = 0; nt < 4; ++nt)
        acc[nt] = __builtin_amdgcn_mfma_f32_16x16x32_bf16(fa.v, bfrag[kc][nt],
                                                          acc[nt], 0, 0, 0);
    }
    int rbase = row0 + (lane >> 4) * 4;
#pragma unroll
    for (int nt = 0; nt < 4; ++nt) {
      int col = nt * 16 + cc;
#pragma unroll
      for (int j = 0; j < 4; ++j) {
        int r = rbase + j;
        if (r < n) h[(size_t)r * DIM_H + col] = f2bf(acc[nt][j]);
      }
    }
  }
}

// ======================= GEMM2: h2(bf16) = relu(agg1) @ W2 =======================
__global__ __launch_bounds__(256) void k_gemm2(const float* __restrict__ a,
                                               const float* __restrict__ W,
                                               ushort* __restrict__ h2, int n) {
  __shared__ float Ws[64][16];
  const int t = threadIdx.x;
  for (int i = t; i < 64 * 16; i += 256) Ws[i >> 4][i & 15] = W[i];
  __syncthreads();
  int r = blockIdx.x * 256 + t;
  if (r >= n) return;
  const float4* ap = (const float4*)(a + (size_t)r * DIM_H);
  float acc[16] = {};
  for (int k4 = 0; k4 < 16; ++k4) {
    float4 v = ap[k4];
    float vv[4] = {fmaxf(v.x, 0.f), fmaxf(v.y, 0.f), fmaxf(v.z, 0.f),
                   fmaxf(v.w, 0.f)};
#pragma unroll
    for (int kk = 0; kk < 4; ++kk) {
      int k = k4 * 4 + kk;
#pragma unroll
      for (int j = 0; j < 16; ++j) acc[j] = fmaf(vv[kk], Ws[k][j], acc[j]);
    }
  }
  ushort4* hp = (ushort4*)(h2 + (size_t)r * DIM_OUT);
#pragma unroll
  for (int q = 0; q < 4; ++q) {
    ushort4 o;
    o.x = f2bf(acc[q * 4 + 0]);
    o.y = f2bf(acc[q * 4 + 1]);
    o.z = f2bf(acc[q * 4 + 2]);
    o.w = f2bf(acc[q * 4 + 3]);
    hp[q] = o;
  }
}

// ======================= gather aggregation =======================

// layer 1: one wave per node. Lane layout: q=lane&15 owns cols 4q..4q+3
// (uint2 = 4 bf16 per row-load); g=lane>>4 processes edge j+g -> 4 edges in
// flight natively. Cross-group reduce via shfl_xor(16/32) at the end.
__global__ __launch_bounds__(256) void k_gather64(const ushort* __restrict__ h,
                                                  const int* __restrict__ srcs,
                                                  const int* __restrict__ rowptr,
                                                  const int* __restrict__ deg,
                                                  const float* __restrict__ dinv,
                                                  const float* __restrict__ b,
                                                  float* __restrict__ out, int n) {
  int node = blockIdx.x * 4 + (threadIdx.x >> 6);
  int lane = threadIdx.x & 63;
  int g = lane >> 4;
  int q = lane & 15;
  if (node >= n) return;
  int start = rowptr[node];
  int cnt = deg[node];
  float dd = dinv[node];
  float a0 = 0.f, a1 = 0.f, a2 = 0.f, a3 = 0.f;
  for (int j0 = 0; j0 < cnt; j0 += 64) {
    int rem = cnt - j0;
    if (rem > 64) rem = 64;
    int s_l = (lane < rem) ? srcs[start + j0 + lane] : 0;
    float w_l = (lane < rem) ? dinv[s_l] * dd : 0.0f;
    for (int j = 0; j < rem; j += 4) {
      int idx = j + g;
      int s = __shfl(s_l, idx);
      float w = __shfl(w_l, idx);  // 0 for idx >= rem
      uint2 hv = *(const uint2*)(h + (size_t)s * DIM_H + q * 4);
      a0 = fmaf(bf2f((ushort)(hv.x & 0xffff)), w, a0);
      a1 = fmaf(bf2f((ushort)(hv.x >> 16)), w, a1);
      a2 = fmaf(bf2f((ushort)(hv.y & 0xffff)), w, a2);
      a3 = fmaf(bf2f((ushort)(hv.y >> 16)), w, a3);
    }
  }
  // sum across the 4 edge-groups
  a0 += __shfl_xor(a0, 16); a0 += __shfl_xor(a0, 32);
  a1 += __shfl_xor(a1, 16); a1 += __shfl_xor(a1, 32);
  a2 += __shfl_xor(a2, 16); a2 += __shfl_xor(a2, 32);
  a3 += __shfl_xor(a3, 16); a3 += __shfl_xor(a3, 32);
  if (lane < 16) {
    // self-loop + bias (added once, after reduction)
    uint2 sv = *(const uint2*)(h + (size_t)node * DIM_H + q * 4);
    float s2 = dd * dd;
    a0 = fmaf(bf2f((ushort)(sv.x & 0xffff)), s2, a0) + b[q * 4 + 0];
    a1 = fmaf(bf2f((ushort)(sv.x >> 16)), s2, a1) + b[q * 4 + 1];
    a2 = fmaf(bf2f((ushort)(sv.y & 0xffff)), s2, a2) + b[q * 4 + 2];
    a3 = fmaf(bf2f((ushort)(sv.y >> 16)), s2, a3) + b[q * 4 + 3];
    *(float4*)(out + (size_t)node * DIM_H + q * 4) = make_float4(a0, a1, a2, a3);
  }
}

// layer 2: 16-lane group per node; fused self+bias+log_softmax. h is bf16.
__global__ __launch_bounds__(256) void k_gather16(const ushort* __restrict__ h,
                                                  const int* __restrict__ srcs,
                                                  const int* __restrict__ rowptr,
                                                  const int* __restrict__ deg,
                                                  const float* __restrict__ dinv,
                                                  const float* __restrict__ b,
                                                  float* __restrict__ out, int n) {
  int node = blockIdx.x * 16 + (threadIdx.x >> 4);
  int lane = threadIdx.x & 15;
  int gbase = (threadIdx.x & 63) & 48;
  if (node >= n) return;
  int start = rowptr[node];
  int cnt = deg[node];
  float dd = dinv[node];
  float acc = bf2f(h[(size_t)node * DIM_OUT + lane]) * dd * dd + b[lane];
  for (int j0 = 0; j0 < cnt; j0 += 16) {
    int rem = cnt - j0;
    if (rem > 16) rem = 16;
    int s_l = (lane < rem) ? srcs[start + j0 + lane] : 0;
    float w_l = dinv[s_l] * dd;
    int j = 0;
    for (; j + 4 <= rem; j += 4) {
      int s0 = __shfl(s_l, gbase + j), s1 = __shfl(s_l, gbase + j + 1);
      int s2 = __shfl(s_l, gbase + j + 2), s3 = __shfl(s_l, gbase + j + 3);
      float w0 = __shfl(w_l, gbase + j), w1 = __shfl(w_l, gbase + j + 1);
      float w2 = __shfl(w_l, gbase + j + 2), w3 = __shfl(w_l, gbase + j + 3);
      float v0 = bf2f(h[(size_t)s0 * DIM_OUT + lane]);
      float v1 = bf2f(h[(size_t)s1 * DIM_OUT + lane]);
      float v2 = bf2f(h[(size_t)s2 * DIM_OUT + lane]);
      float v3 = bf2f(h[(size_t)s3 * DIM_OUT + lane]);
      acc = fmaf(v0, w0, acc);
      acc = fmaf(v1, w1, acc);
      acc = fmaf(v2, w2, acc);
      acc = fmaf(v3, w3, acc);
    }
    for (; j < rem; ++j) {
      int s = __shfl(s_l, gbase + j);
      float w = __shfl(w_l, gbase + j);
      acc = fmaf(bf2f(h[(size_t)s * DIM_OUT + lane]), w, acc);
    }
  }
  float m = acc;
#pragma unroll
  for (int off = 1; off < 16; off <<= 1) m = fmaxf(m, __shfl_xor(m, off));
  float e = expf(acc - m);
  float ssum = e;
#pragma unroll
  for (int off = 1; off < 16; off <<= 1) ssum += __shfl_xor(ssum, off);
  out[(size_t)node * DIM_OUT + lane] = acc - m - logf(ssum);
}

// ======================= launch =======================

extern "C" void kernel_launch(void* const* d_in, const int* in_sizes, int n_in,
                              void* d_out, int out_size, void* d_ws, size_t ws_size,
                              hipStream_t stream) {
  const float* x  = (const float*)d_in[0];
  const int*   ei = (const int*)d_in[1];
  const float* W1 = (const float*)d_in[2];
  const float* b1 = (const float*)d_in[3];
  const float* W2 = (const float*)d_in[4];
  const float* b2 = (const float*)d_in[5];
  float* out = (float*)d_out;

  const int n = in_sizes[0] / DIM_IN;  // 100000
  const int E = in_sizes[1] / 2;       // 1600000
  const int* srcv = ei;
  const int* dstv = ei + E;
  const int NB = (n + 255) >> NBSHIFT;  // 391

  char* wsb = (char*)d_ws;
  int* degi    = (int*)wsb;   wsb += (size_t)n * 4;
  int* rowptr  = (int*)wsb;   wsb += (size_t)n * 4;
  float* dinv  = (float*)wsb; wsb += (size_t)n * 4;
  int* gbhist  = (int*)wsb;   wsb += 512 * 4;
  int* bbase   = (int*)wsb;   wsb += 512 * 4;
  int* bcursor = (int*)wsb;   wsb += 512 * 4;
  int* srcs    = (int*)wsb;   wsb += (size_t)E * 4;
  ushort* h1   = (ushort*)wsb; wsb += (size_t)n * DIM_H * 2;
  float* agg1  = (float*)wsb;  wsb += (size_t)n * DIM_H * 4;
  ushort* h2   = (ushort*)wsb; wsb += (size_t)n * DIM_OUT * 2;
  // pairs (E int2 = 12.8 MB) aliases agg1 (25.6 MB): dead before k_gather64 writes
  int2* pairs = (int2*)agg1;

  // ---- CSR build ----
  hipMemsetAsync(gbhist, 0, 512 * 4, stream);
  k_bhist<<<256, 256, 0, stream>>>(dstv, E, NB, gbhist);
  k_bscan<<<1, 512, 0, stream>>>(gbhist, NB, bbase, bcursor);
  k_part<<<(E + 8191) / 8192, 256, 0, stream>>>(srcv, dstv, E, NB, bcursor, pairs);
  k_csr<<<NB, 256, 0, stream>>>(pairs, gbhist, bbase, n, degi, dinv, rowptr, srcs);

  // ---- layer 1 ----
  k_gemm1m<<<512, 256, 0, stream>>>(x, W1, h1, n, (n + 15) / 16);
  k_gather64<<<(n + 3) / 4, 256, 0, stream>>>(h1, srcs, rowptr, degi, dinv, b1,
                                              agg1, n);

  // ---- layer 2 ----
  k_gemm2<<<(n + 255) / 256, 256, 0, stream>>>(agg1, W2, h2, n);
  k_gather16<<<(n + 15) / 16, 256, 0, stream>>>(h2, srcs, rowptr, degi, dinv, b2,
                                                out, n);
}

// Round 7
// 190.512 us; speedup vs baseline: 1.1396x; 1.1396x over previous
//
#include <hip/hip_runtime.h>
#include <math.h>

#define DIM_IN 128
#define DIM_H 64
#define DIM_OUT 16
#define NBSHIFT 8  // 256 nodes per bucket

typedef __attribute__((ext_vector_type(8))) short bf16x8;
typedef __attribute__((ext_vector_type(4))) float f32x4;

__device__ __forceinline__ ushort f2bf(float f) {
  uint u = __float_as_uint(f);
  return (ushort)((u + 0x7FFF + ((u >> 16) & 1)) >> 16);
}
__device__ __forceinline__ float bf2f(ushort s) {
  return __uint_as_float(((uint)s) << 16);
}
__device__ __forceinline__ uint cvtpk(float lo, float hi) {
  uint r;
  asm("v_cvt_pk_bf16_f32 %0, %1, %2" : "=v"(r) : "v"(lo), "v"(hi));
  return r;
}

// ======================= bucket histogram =======================
__global__ __launch_bounds__(256) void k_bhist(const int* __restrict__ dst, int E,
                                               int NB, int* __restrict__ gbhist) {
  __shared__ int lh[512];
  int t = threadIdx.x;
  lh[t] = 0;
  lh[t + 256] = 0;
  __syncthreads();
  for (int i = blockIdx.x * 256 + t; i < E; i += gridDim.x * 256)
    atomicAdd(&lh[dst[i] >> NBSHIFT], 1);
  __syncthreads();
  for (int b = t; b < NB; b += 256) {
    int c = lh[b];
    if (c) atomicAdd(&gbhist[b], c);
  }
}

// exclusive scan of gbhist[NB] -> bbase, bcursor (NB <= 512), single block
__global__ __launch_bounds__(512) void k_bscan(const int* __restrict__ gbhist, int NB,
                                               int* __restrict__ bbase,
                                               int* __restrict__ bcursor) {
  __shared__ int sb[512];
  int t = threadIdx.x;
  int v = (t < NB) ? gbhist[t] : 0;
  sb[t] = v;
  __syncthreads();
  for (int off = 1; off < 512; off <<= 1) {
    int add = (t >= off) ? sb[t - off] : 0;
    __syncthreads();
    sb[t] += add;
    __syncthreads();
  }
  if (t < NB) {
    int e = sb[t] - v;
    bbase[t] = e;
    bcursor[t] = e;
  }
}

// ======================= partition into bucket regions =======================
__global__ __launch_bounds__(256) void k_part(const int* __restrict__ src,
                                              const int* __restrict__ dst, int E,
                                              int NB, int* __restrict__ bcursor,
                                              int2* __restrict__ pairs) {
  __shared__ int lh[512];
  __shared__ int lcur[512];
  int t = threadIdx.x;
  lh[t] = 0;
  lh[t + 256] = 0;
  __syncthreads();
  int e0 = blockIdx.x * 8192;
  int e1 = min(E, e0 + 8192);
  for (int i = e0 + t; i < e1; i += 256) atomicAdd(&lh[dst[i] >> NBSHIFT], 1);
  __syncthreads();
  for (int b = t; b < NB; b += 256) {
    int c = lh[b];
    lcur[b] = c ? atomicAdd(&bcursor[b], c) : 0;
  }
  __syncthreads();
  for (int i = e0 + t; i < e1; i += 256) {
    int d = dst[i];
    int pos = atomicAdd(&lcur[d >> NBSHIFT], 1);
    pairs[pos] = make_int2(src[i], d);
  }
}

// ======================= per-bucket CSR + deg + dinv (no sort) ==============
__global__ __launch_bounds__(256) void k_csr(const int2* __restrict__ pairs,
                                             const int* __restrict__ gbhist,
                                             const int* __restrict__ bbase, int n,
                                             int* __restrict__ degi,
                                             float* __restrict__ dinv,
                                             int* __restrict__ rowptr,
                                             int* __restrict__ srcs) {
  __shared__ int nh[256];
  __shared__ int ncur[256];
  int t = threadIdx.x;
  int b = blockIdx.x;
  int base = bbase[b];
  int cnt = gbhist[b];
  nh[t] = 0;
  __syncthreads();
  for (int i = t; i < cnt; i += 256) atomicAdd(&nh[pairs[base + i].y & 255], 1);
  __syncthreads();
  int node = (b << NBSHIFT) + t;
  int v = nh[t];
  if (node < n) {
    degi[node] = v;
    dinv[node] = rsqrtf((float)v + 1.0f);
  }
  __syncthreads();
  for (int off = 1; off < 256; off <<= 1) {
    int add = (t >= off) ? nh[t - off] : 0;
    __syncthreads();
    nh[t] += add;
    __syncthreads();
  }
  int excl = nh[t] - v;
  if (node < n) rowptr[node] = base + excl;
  ncur[t] = base + excl;
  __syncthreads();
  for (int i = t; i < cnt; i += 256) {
    int2 p = pairs[base + i];
    int pos = atomicAdd(&ncur[p.y & 255], 1);
    srcs[pos] = p.x;
  }
}

// ======================= GEMM1 (MFMA bf16): h1 = x @ W1 =======================
__global__ __launch_bounds__(256, 4) void k_gemm1m(const float* __restrict__ x,
                                                   const float* __restrict__ W,
                                                   ushort* __restrict__ h, int n,
                                                   int nTiles) {
  const int t = threadIdx.x;
  const int lane = t & 63;
  const int wid = blockIdx.x * 4 + (t >> 6);
  const int nW = gridDim.x * 4;
  const int cc = lane & 15;        // A row offset / B,D col offset
  const int kb = (lane >> 4) * 8;  // k-octet within 32-chunk

  bf16x8 bfrag[4][4];
#pragma unroll
  for (int kc = 0; kc < 4; ++kc)
#pragma unroll
    for (int nt = 0; nt < 4; ++nt) {
      union { bf16x8 v; uint u[4]; } fb;
#pragma unroll
      for (int j = 0; j < 4; ++j) {
        float lo = W[(size_t)(kc * 32 + kb + 2 * j) * DIM_H + nt * 16 + cc];
        float hi = W[(size_t)(kc * 32 + kb + 2 * j + 1) * DIM_H + nt * 16 + cc];
        fb.u[j] = cvtpk(lo, hi);
      }
      bfrag[kc][nt] = fb.v;
    }

  for (int tile = wid; tile < nTiles; tile += nW) {
    int row0 = tile * 16;
    int ra = row0 + cc;
    if (ra > n - 1) ra = n - 1;
    const float* xp = x + (size_t)ra * DIM_IN;
    f32x4 acc[4] = {{0.f, 0.f, 0.f, 0.f},
                    {0.f, 0.f, 0.f, 0.f},
                    {0.f, 0.f, 0.f, 0.f},
                    {0.f, 0.f, 0.f, 0.f}};
#pragma unroll
    for (int kc = 0; kc < 4; ++kc) {
      float4 a0 = *(const float4*)(xp + kc * 32 + kb);
      float4 a1 = *(const float4*)(xp + kc * 32 + kb + 4);
      union { bf16x8 v; uint u[4]; } fa;
      fa.u[0] = cvtpk(a0.x, a0.y);
      fa.u[1] = cvtpk(a0.z, a0.w);
      fa.u[2] = cvtpk(a1.x, a1.y);
      fa.u[3] = cvtpk(a1.z, a1.w);
#pragma unroll
      for (int nt = 0; nt < 4; ++nt)
        acc[nt] = __builtin_amdgcn_mfma_f32_16x16x32_bf16(fa.v, bfrag[kc][nt],
                                                          acc[nt], 0, 0, 0);
    }
    int rbase = row0 + (lane >> 4) * 4;
#pragma unroll
    for (int nt = 0; nt < 4; ++nt) {
      int col = nt * 16 + cc;
#pragma unroll
      for (int j = 0; j < 4; ++j) {
        int r = rbase + j;
        if (r < n) h[(size_t)r * DIM_H + col] = f2bf(acc[nt][j]);
      }
    }
  }
}

// ========== gather64 fused with relu + GEMM2: h2 = relu(agg) @ W2 ==========
// Lane (g=lane>>4, q=lane&15): q owns cols 4q..4q+3, g processes edges j+g and
// j+4+g (8 edges in flight/wave). After shfl_xor(16/32) all-reduce every lane
// holds the full agg row slice; epilogue: self+bias+relu, 4x4 W2 fragment
// multiply, shfl_xor reduce over q -> group g holds outputs 4g..4g+3.
__global__ __launch_bounds__(256) void k_gather64f(const ushort* __restrict__ h,
                                                   const int* __restrict__ srcs,
                                                   const int* __restrict__ rowptr,
                                                   const int* __restrict__ deg,
                                                   const float* __restrict__ dinv,
                                                   const float* __restrict__ b,
                                                   const float* __restrict__ W2,
                                                   ushort* __restrict__ h2, int n) {
  int node = blockIdx.x * 4 + (threadIdx.x >> 6);
  int lane = threadIdx.x & 63;
  int g = lane >> 4;
  int q = lane & 15;
  if (node >= n) return;
  // W2 fragment: rows 4q..4q+3, cols 4g..4g+3 (L2-hot, loop-invariant)
  float4 w2r[4];
#pragma unroll
  for (int c = 0; c < 4; ++c)
    w2r[c] = *(const float4*)(W2 + (size_t)(4 * q + c) * DIM_OUT + 4 * g);

  int start = rowptr[node];
  int cnt = deg[node];
  float dd = dinv[node];
  float a0 = 0.f, a1 = 0.f, a2 = 0.f, a3 = 0.f;
  for (int j0 = 0; j0 < cnt; j0 += 64) {
    int rem = cnt - j0;
    if (rem > 64) rem = 64;
    int s_l = (lane < rem) ? srcs[start + j0 + lane] : 0;
    float w_l = (lane < rem) ? dinv[s_l] * dd : 0.0f;
    for (int j = 0; j < rem; j += 8) {
      int i0 = j + g;       // <= 59
      int i1 = j + 4 + g;   // <= 63
      int s0 = __shfl(s_l, i0);
      float w0 = __shfl(w_l, i0);
      int s1 = __shfl(s_l, i1);
      float w1 = __shfl(w_l, i1);
      uint2 v0 = *(const uint2*)(h + (size_t)s0 * DIM_H + q * 4);
      uint2 v1 = *(const uint2*)(h + (size_t)s1 * DIM_H + q * 4);
      a0 = fmaf(bf2f((ushort)(v0.x & 0xffff)), w0, a0);
      a1 = fmaf(bf2f((ushort)(v0.x >> 16)), w0, a1);
      a2 = fmaf(bf2f((ushort)(v0.y & 0xffff)), w0, a2);
      a3 = fmaf(bf2f((ushort)(v0.y >> 16)), w0, a3);
      a0 = fmaf(bf2f((ushort)(v1.x & 0xffff)), w1, a0);
      a1 = fmaf(bf2f((ushort)(v1.x >> 16)), w1, a1);
      a2 = fmaf(bf2f((ushort)(v1.y & 0xffff)), w1, a2);
      a3 = fmaf(bf2f((ushort)(v1.y >> 16)), w1, a3);
    }
  }
  // all-reduce across the 4 edge-groups (every lane gets the full sums)
  a0 += __shfl_xor(a0, 16); a0 += __shfl_xor(a0, 32);
  a1 += __shfl_xor(a1, 16); a1 += __shfl_xor(a1, 32);
  a2 += __shfl_xor(a2, 16); a2 += __shfl_xor(a2, 32);
  a3 += __shfl_xor(a3, 16); a3 += __shfl_xor(a3, 32);
  // self-loop + bias + relu (all lanes; groups redundant but cheap)
  uint2 sv = *(const uint2*)(h + (size_t)node * DIM_H + q * 4);
  float s2 = dd * dd;
  a0 = fmaxf(fmaf(bf2f((ushort)(sv.x & 0xffff)), s2, a0) + b[4 * q + 0], 0.f);
  a1 = fmaxf(fmaf(bf2f((ushort)(sv.x >> 16)), s2, a1) + b[4 * q + 1], 0.f);
  a2 = fmaxf(fmaf(bf2f((ushort)(sv.y & 0xffff)), s2, a2) + b[4 * q + 2], 0.f);
  a3 = fmaxf(fmaf(bf2f((ushort)(sv.y >> 16)), s2, a3) + b[4 * q + 3], 0.f);
  // GEMM2 partials: p[j] = sum_c a_c * W2[4q+c][4g+j]
  float p0 = a0 * w2r[0].x + a1 * w2r[1].x + a2 * w2r[2].x + a3 * w2r[3].x;
  float p1 = a0 * w2r[0].y + a1 * w2r[1].y + a2 * w2r[2].y + a3 * w2r[3].y;
  float p2 = a0 * w2r[0].z + a1 * w2r[1].z + a2 * w2r[2].z + a3 * w2r[3].z;
  float p3 = a0 * w2r[0].w + a1 * w2r[1].w + a2 * w2r[2].w + a3 * w2r[3].w;
#pragma unroll
  for (int off = 1; off < 16; off <<= 1) {
    p0 += __shfl_xor(p0, off);
    p1 += __shfl_xor(p1, off);
    p2 += __shfl_xor(p2, off);
    p3 += __shfl_xor(p3, off);
  }
  if (q == 0) {
    uint lo = cvtpk(p0, p1);
    uint hi = cvtpk(p2, p3);
    *(uint2*)(h2 + (size_t)node * DIM_OUT + 4 * g) = make_uint2(lo, hi);
  }
}

// layer 2: 16-lane group per node; fused self+bias+log_softmax. h is bf16.
__global__ __launch_bounds__(256) void k_gather16(const ushort* __restrict__ h,
                                                  const int* __restrict__ srcs,
                                                  const int* __restrict__ rowptr,
                                                  const int* __restrict__ deg,
                                                  const float* __restrict__ dinv,
                                                  const float* __restrict__ b,
                                                  float* __restrict__ out, int n) {
  int node = blockIdx.x * 16 + (threadIdx.x >> 4);
  int lane = threadIdx.x & 15;
  int gbase = (threadIdx.x & 63) & 48;
  if (node >= n) return;
  int start = rowptr[node];
  int cnt = deg[node];
  float dd = dinv[node];
  float acc = bf2f(h[(size_t)node * DIM_OUT + lane]) * dd * dd + b[lane];
  for (int j0 = 0; j0 < cnt; j0 += 16) {
    int rem = cnt - j0;
    if (rem > 16) rem = 16;
    int s_l = (lane < rem) ? srcs[start + j0 + lane] : 0;
    float w_l = dinv[s_l] * dd;
    int j = 0;
    for (; j + 4 <= rem; j += 4) {
      int s0 = __shfl(s_l, gbase + j), s1 = __shfl(s_l, gbase + j + 1);
      int s2 = __shfl(s_l, gbase + j + 2), s3 = __shfl(s_l, gbase + j + 3);
      float w0 = __shfl(w_l, gbase + j), w1 = __shfl(w_l, gbase + j + 1);
      float w2 = __shfl(w_l, gbase + j + 2), w3 = __shfl(w_l, gbase + j + 3);
      float v0 = bf2f(h[(size_t)s0 * DIM_OUT + lane]);
      float v1 = bf2f(h[(size_t)s1 * DIM_OUT + lane]);
      float v2 = bf2f(h[(size_t)s2 * DIM_OUT + lane]);
      float v3 = bf2f(h[(size_t)s3 * DIM_OUT + lane]);
      acc = fmaf(v0, w0, acc);
      acc = fmaf(v1, w1, acc);
      acc = fmaf(v2, w2, acc);
      acc = fmaf(v3, w3, acc);
    }
    for (; j < rem; ++j) {
      int s = __shfl(s_l, gbase + j);
      float w = __shfl(w_l, gbase + j);
      acc = fmaf(bf2f(h[(size_t)s * DIM_OUT + lane]), w, acc);
    }
  }
  float m = acc;
#pragma unroll
  for (int off = 1; off < 16; off <<= 1) m = fmaxf(m, __shfl_xor(m, off));
  float e = expf(acc - m);
  float ssum = e;
#pragma unroll
  for (int off = 1; off < 16; off <<= 1) ssum += __shfl_xor(ssum, off);
  out[(size_t)node * DIM_OUT + lane] = acc - m - logf(ssum);
}

// ======================= launch =======================

extern "C" void kernel_launch(void* const* d_in, const int* in_sizes, int n_in,
                              void* d_out, int out_size, void* d_ws, size_t ws_size,
                              hipStream_t stream) {
  const float* x  = (const float*)d_in[0];
  const int*   ei = (const int*)d_in[1];
  const float* W1 = (const float*)d_in[2];
  const float* b1 = (const float*)d_in[3];
  const float* W2 = (const float*)d_in[4];
  const float* b2 = (const float*)d_in[5];
  float* out = (float*)d_out;

  const int n = in_sizes[0] / DIM_IN;  // 100000
  const int E = in_sizes[1] / 2;       // 1600000
  const int* srcv = ei;
  const int* dstv = ei + E;
  const int NB = (n + 255) >> NBSHIFT;  // 391

  char* wsb = (char*)d_ws;
  int* degi    = (int*)wsb;   wsb += (size_t)n * 4;
  int* rowptr  = (int*)wsb;   wsb += (size_t)n * 4;
  float* dinv  = (float*)wsb; wsb += (size_t)n * 4;
  int* gbhist  = (int*)wsb;   wsb += 512 * 4;
  int* bbase   = (int*)wsb;   wsb += 512 * 4;
  int* bcursor = (int*)wsb;   wsb += 512 * 4;
  int* srcs    = (int*)wsb;   wsb += (size_t)E * 4;
  ushort* h1   = (ushort*)wsb; wsb += (size_t)n * DIM_H * 2;
  float* scratch = (float*)wsb; wsb += (size_t)n * DIM_H * 4;  // pairs live here
  ushort* h2   = (ushort*)wsb; wsb += (size_t)n * DIM_OUT * 2;
  int2* pairs = (int2*)scratch;

  // ---- CSR build ----
  hipMemsetAsync(gbhist, 0, 512 * 4, stream);
  k_bhist<<<256, 256, 0, stream>>>(dstv, E, NB, gbhist);
  k_bscan<<<1, 512, 0, stream>>>(gbhist, NB, bbase, bcursor);
  k_part<<<(E + 8191) / 8192, 256, 0, stream>>>(srcv, dstv, E, NB, bcursor, pairs);
  k_csr<<<NB, 256, 0, stream>>>(pairs, gbhist, bbase, n, degi, dinv, rowptr, srcs);

  // ---- layer 1 (+ fused relu + GEMM2) ----
  k_gemm1m<<<512, 256, 0, stream>>>(x, W1, h1, n, (n + 15) / 16);
  k_gather64f<<<(n + 3) / 4, 256, 0, stream>>>(h1, srcs, rowptr, degi, dinv, b1,
                                               W2, h2, n);

  // ---- layer 2 aggregation + log_softmax ----
  k_gather16<<<(n + 15) / 16, 256, 0, stream>>>(h2, srcs, rowptr, degi, dinv, b2,
                                                out, n);
}

// Round 8
// 163.732 us; speedup vs baseline: 1.3260x; 1.1636x over previous
//
#include <hip/hip_runtime.h>
#include <math.h>

#define DIM_IN 128
#define DIM_H 64
#define DIM_OUT 16
#define NBSHIFT 8  // 256 nodes per bucket

typedef __attribute__((ext_vector_type(8))) short bf16x8;
typedef __attribute__((ext_vector_type(4))) float f32x4;

__device__ __forceinline__ ushort f2bf(float f) {
  uint u = __float_as_uint(f);
  return (ushort)((u + 0x7FFF + ((u >> 16) & 1)) >> 16);
}
__device__ __forceinline__ float bf2f(ushort s) {
  return __uint_as_float(((uint)s) << 16);
}
__device__ __forceinline__ uint cvtpk(float lo, float hi) {
  uint r;
  asm("v_cvt_pk_bf16_f32 %0, %1, %2" : "=v"(r) : "v"(lo), "v"(hi));
  return r;
}

// ======================= bucket histogram =======================
__global__ __launch_bounds__(256) void k_bhist(const int* __restrict__ dst, int E,
                                               int NB, int* __restrict__ gbhist) {
  __shared__ int lh[512];
  int t = threadIdx.x;
  lh[t] = 0;
  lh[t + 256] = 0;
  __syncthreads();
  for (int i = blockIdx.x * 256 + t; i < E; i += gridDim.x * 256)
    atomicAdd(&lh[dst[i] >> NBSHIFT], 1);
  __syncthreads();
  for (int b = t; b < NB; b += 256) {
    int c = lh[b];
    if (c) atomicAdd(&gbhist[b], c);
  }
}

// exclusive scan of gbhist[NB] -> bbase, bcursor (NB <= 512), single block
__global__ __launch_bounds__(512) void k_bscan(const int* __restrict__ gbhist, int NB,
                                               int* __restrict__ bbase,
                                               int* __restrict__ bcursor) {
  __shared__ int sb[512];
  int t = threadIdx.x;
  int v = (t < NB) ? gbhist[t] : 0;
  sb[t] = v;
  __syncthreads();
  for (int off = 1; off < 512; off <<= 1) {
    int add = (t >= off) ? sb[t - off] : 0;
    __syncthreads();
    sb[t] += add;
    __syncthreads();
  }
  if (t < NB) {
    int e = sb[t] - v;
    bbase[t] = e;
    bcursor[t] = e;
  }
}

// ======================= partition into bucket regions =======================
__global__ __launch_bounds__(256) void k_part(const int* __restrict__ src,
                                              const int* __restrict__ dst, int E,
                                              int NB, int* __restrict__ bcursor,
                                              int2* __restrict__ pairs) {
  __shared__ int lh[512];
  __shared__ int lcur[512];
  int t = threadIdx.x;
  lh[t] = 0;
  lh[t + 256] = 0;
  __syncthreads();
  int e0 = blockIdx.x * 8192;
  int e1 = min(E, e0 + 8192);
  for (int i = e0 + t; i < e1; i += 256) atomicAdd(&lh[dst[i] >> NBSHIFT], 1);
  __syncthreads();
  for (int b = t; b < NB; b += 256) {
    int c = lh[b];
    lcur[b] = c ? atomicAdd(&bcursor[b], c) : 0;
  }
  __syncthreads();
  for (int i = e0 + t; i < e1; i += 256) {
    int d = dst[i];
    int pos = atomicAdd(&lcur[d >> NBSHIFT], 1);
    pairs[pos] = make_int2(src[i], d);
  }
}

// ======================= per-bucket CSR + deg + dinv (no sort) ==============
__global__ __launch_bounds__(256) void k_csr(const int2* __restrict__ pairs,
                                             const int* __restrict__ gbhist,
                                             const int* __restrict__ bbase, int n,
                                             int* __restrict__ degi,
                                             float* __restrict__ dinv,
                                             int* __restrict__ rowptr,
                                             int* __restrict__ srcs) {
  __shared__ int nh[256];
  __shared__ int ncur[256];
  int t = threadIdx.x;
  int b = blockIdx.x;
  int base = bbase[b];
  int cnt = gbhist[b];
  nh[t] = 0;
  __syncthreads();
  for (int i = t; i < cnt; i += 256) atomicAdd(&nh[pairs[base + i].y & 255], 1);
  __syncthreads();
  int node = (b << NBSHIFT) + t;
  int v = nh[t];
  if (node < n) {
    degi[node] = v;
    dinv[node] = rsqrtf((float)v + 1.0f);
  }
  __syncthreads();
  for (int off = 1; off < 256; off <<= 1) {
    int add = (t >= off) ? nh[t - off] : 0;
    __syncthreads();
    nh[t] += add;
    __syncthreads();
  }
  int excl = nh[t] - v;
  if (node < n) rowptr[node] = base + excl;
  ncur[t] = base + excl;
  __syncthreads();
  for (int i = t; i < cnt; i += 256) {
    int2 p = pairs[base + i];
    int pos = atomicAdd(&ncur[p.y & 255], 1);
    srcs[pos] = p.x;
  }
}

// ======================= GEMM1 (MFMA bf16): h1 = x @ W1 =======================
__global__ __launch_bounds__(256, 4) void k_gemm1m(const float* __restrict__ x,
                                                   const float* __restrict__ W,
                                                   ushort* __restrict__ h, int n,
                                                   int nTiles) {
  const int t = threadIdx.x;
  const int lane = t & 63;
  const int wid = blockIdx.x * 4 + (t >> 6);
  const int nW = gridDim.x * 4;
  const int cc = lane & 15;        // A row offset / B,D col offset
  const int kb = (lane >> 4) * 8;  // k-octet within 32-chunk

  bf16x8 bfrag[4][4];
#pragma unroll
  for (int kc = 0; kc < 4; ++kc)
#pragma unroll
    for (int nt = 0; nt < 4; ++nt) {
      union { bf16x8 v; uint u[4]; } fb;
#pragma unroll
      for (int j = 0; j < 4; ++j) {
        float lo = W[(size_t)(kc * 32 + kb + 2 * j) * DIM_H + nt * 16 + cc];
        float hi = W[(size_t)(kc * 32 + kb + 2 * j + 1) * DIM_H + nt * 16 + cc];
        fb.u[j] = cvtpk(lo, hi);
      }
      bfrag[kc][nt] = fb.v;
    }

  for (int tile = wid; tile < nTiles; tile += nW) {
    int row0 = tile * 16;
    int ra = row0 + cc;
    if (ra > n - 1) ra = n - 1;
    const float* xp = x + (size_t)ra * DIM_IN;
    f32x4 acc[4] = {{0.f, 0.f, 0.f, 0.f},
                    {0.f, 0.f, 0.f, 0.f},
                    {0.f, 0.f, 0.f, 0.f},
                    {0.f, 0.f, 0.f, 0.f}};
#pragma unroll
    for (int kc = 0; kc < 4; ++kc) {
      float4 a0 = *(const float4*)(xp + kc * 32 + kb);
      float4 a1 = *(const float4*)(xp + kc * 32 + kb + 4);
      union { bf16x8 v; uint u[4]; } fa;
      fa.u[0] = cvtpk(a0.x, a0.y);
      fa.u[1] = cvtpk(a0.z, a0.w);
      fa.u[2] = cvtpk(a1.x, a1.y);
      fa.u[3] = cvtpk(a1.z, a1.w);
#pragma unroll
      for (int nt = 0; nt < 4; ++nt)
        acc[nt] = __builtin_amdgcn_mfma_f32_16x16x32_bf16(fa.v, bfrag[kc][nt],
                                                          acc[nt], 0, 0, 0);
    }
    int rbase = row0 + (lane >> 4) * 4;
#pragma unroll
    for (int nt = 0; nt < 4; ++nt) {
      int col = nt * 16 + cc;
#pragma unroll
      for (int j = 0; j < 4; ++j) {
        int r = rbase + j;
        if (r < n) h[(size_t)r * DIM_H + col] = f2bf(acc[nt][j]);
      }
    }
  }
}

// ======================= GEMM2: h2(bf16) = relu(agg1) @ W2 =======================
__global__ __launch_bounds__(256) void k_gemm2(const float* __restrict__ a,
                                               const float* __restrict__ W,
                                               ushort* __restrict__ h2, int n) {
  __shared__ float Ws[64][16];
  const int t = threadIdx.x;
  for (int i = t; i < 64 * 16; i += 256) Ws[i >> 4][i & 15] = W[i];
  __syncthreads();
  int r = blockIdx.x * 256 + t;
  if (r >= n) return;
  const float4* ap = (const float4*)(a + (size_t)r * DIM_H);
  float acc[16] = {};
  for (int k4 = 0; k4 < 16; ++k4) {
    float4 v = ap[k4];
    float vv[4] = {fmaxf(v.x, 0.f), fmaxf(v.y, 0.f), fmaxf(v.z, 0.f),
                   fmaxf(v.w, 0.f)};
#pragma unroll
    for (int kk = 0; kk < 4; ++kk) {
      int k = k4 * 4 + kk;
#pragma unroll
      for (int j = 0; j < 16; ++j) acc[j] = fmaf(vv[kk], Ws[k][j], acc[j]);
    }
  }
  ushort4* hp = (ushort4*)(h2 + (size_t)r * DIM_OUT);
#pragma unroll
  for (int q = 0; q < 4; ++q) {
    ushort4 o;
    o.x = f2bf(acc[q * 4 + 0]);
    o.y = f2bf(acc[q * 4 + 1]);
    o.z = f2bf(acc[q * 4 + 2]);
    o.w = f2bf(acc[q * 4 + 3]);
    hp[q] = o;
  }
}

// ======================= gather aggregation =======================

// layer 1: one wave per node; lane = column. 8 loads in flight (padded lanes
// carry s=0,w=0 -> row-0 loads stay cache-hot and contribute nothing).
__global__ __launch_bounds__(256) void k_gather64(const ushort* __restrict__ h,
                                                  const int* __restrict__ srcs,
                                                  const int* __restrict__ rowptr,
                                                  const int* __restrict__ deg,
                                                  const float* __restrict__ dinv,
                                                  const float* __restrict__ b,
                                                  float* __restrict__ out, int n) {
  int node = blockIdx.x * 4 + (threadIdx.x >> 6);
  int lane = threadIdx.x & 63;
  if (node >= n) return;
  int start = rowptr[node];
  int cnt = deg[node];
  float dd = dinv[node];
  float acc = bf2f(h[(size_t)node * DIM_H + lane]) * dd * dd + b[lane];
  for (int j0 = 0; j0 < cnt; j0 += 64) {
    int rem = cnt - j0;
    if (rem > 64) rem = 64;
    int s_l = (lane < rem) ? srcs[start + j0 + lane] : 0;
    float w_l = (lane < rem) ? dinv[s_l] * dd : 0.0f;
    for (int j = 0; j < rem; j += 8) {
      int s0 = __shfl(s_l, j + 0), s1 = __shfl(s_l, j + 1);
      int s2 = __shfl(s_l, j + 2), s3 = __shfl(s_l, j + 3);
      int s4 = __shfl(s_l, j + 4), s5 = __shfl(s_l, j + 5);
      int s6 = __shfl(s_l, j + 6), s7 = __shfl(s_l, j + 7);
      float w0 = __shfl(w_l, j + 0), w1 = __shfl(w_l, j + 1);
      float w2 = __shfl(w_l, j + 2), w3 = __shfl(w_l, j + 3);
      float w4 = __shfl(w_l, j + 4), w5 = __shfl(w_l, j + 5);
      float w6 = __shfl(w_l, j + 6), w7 = __shfl(w_l, j + 7);
      float v0 = bf2f(h[(size_t)s0 * DIM_H + lane]);
      float v1 = bf2f(h[(size_t)s1 * DIM_H + lane]);
      float v2 = bf2f(h[(size_t)s2 * DIM_H + lane]);
      float v3 = bf2f(h[(size_t)s3 * DIM_H + lane]);
      float v4 = bf2f(h[(size_t)s4 * DIM_H + lane]);
      float v5 = bf2f(h[(size_t)s5 * DIM_H + lane]);
      float v6 = bf2f(h[(size_t)s6 * DIM_H + lane]);
      float v7 = bf2f(h[(size_t)s7 * DIM_H + lane]);
      acc = fmaf(v0, w0, acc);
      acc = fmaf(v1, w1, acc);
      acc = fmaf(v2, w2, acc);
      acc = fmaf(v3, w3, acc);
      acc = fmaf(v4, w4, acc);
      acc = fmaf(v5, w5, acc);
      acc = fmaf(v6, w6, acc);
      acc = fmaf(v7, w7, acc);
    }
  }
  out[(size_t)node * DIM_H + lane] = acc;
}

// layer 2: 16-lane group per node; fused self+bias+log_softmax; 8-deep MLP.
__global__ __launch_bounds__(256) void k_gather16(const ushort* __restrict__ h,
                                                  const int* __restrict__ srcs,
                                                  const int* __restrict__ rowptr,
                                                  const int* __restrict__ deg,
                                                  const float* __restrict__ dinv,
                                                  const float* __restrict__ b,
                                                  float* __restrict__ out, int n) {
  int node = blockIdx.x * 16 + (threadIdx.x >> 4);
  int lane = threadIdx.x & 15;
  int gbase = (threadIdx.x & 63) & 48;
  if (node >= n) return;
  int start = rowptr[node];
  int cnt = deg[node];
  float dd = dinv[node];
  float acc = bf2f(h[(size_t)node * DIM_OUT + lane]) * dd * dd + b[lane];
  for (int j0 = 0; j0 < cnt; j0 += 16) {
    int rem = cnt - j0;
    if (rem > 16) rem = 16;
    int s_l = (lane < rem) ? srcs[start + j0 + lane] : 0;
    float w_l = (lane < rem) ? dinv[s_l] * dd : 0.0f;
    for (int j = 0; j < rem; j += 8) {
      int s0 = __shfl(s_l, gbase + j + 0), s1 = __shfl(s_l, gbase + j + 1);
      int s2 = __shfl(s_l, gbase + j + 2), s3 = __shfl(s_l, gbase + j + 3);
      int s4 = __shfl(s_l, gbase + j + 4), s5 = __shfl(s_l, gbase + j + 5);
      int s6 = __shfl(s_l, gbase + j + 6), s7 = __shfl(s_l, gbase + j + 7);
      float w0 = __shfl(w_l, gbase + j + 0), w1 = __shfl(w_l, gbase + j + 1);
      float w2 = __shfl(w_l, gbase + j + 2), w3 = __shfl(w_l, gbase + j + 3);
      float w4 = __shfl(w_l, gbase + j + 4), w5 = __shfl(w_l, gbase + j + 5);
      float w6 = __shfl(w_l, gbase + j + 6), w7 = __shfl(w_l, gbase + j + 7);
      float v0 = bf2f(h[(size_t)s0 * DIM_OUT + lane]);
      float v1 = bf2f(h[(size_t)s1 * DIM_OUT + lane]);
      float v2 = bf2f(h[(size_t)s2 * DIM_OUT + lane]);
      float v3 = bf2f(h[(size_t)s3 * DIM_OUT + lane]);
      float v4 = bf2f(h[(size_t)s4 * DIM_OUT + lane]);
      float v5 = bf2f(h[(size_t)s5 * DIM_OUT + lane]);
      float v6 = bf2f(h[(size_t)s6 * DIM_OUT + lane]);
      float v7 = bf2f(h[(size_t)s7 * DIM_OUT + lane]);
      acc = fmaf(v0, w0, acc);
      acc = fmaf(v1, w1, acc);
      acc = fmaf(v2, w2, acc);
      acc = fmaf(v3, w3, acc);
      acc = fmaf(v4, w4, acc);
      acc = fmaf(v5, w5, acc);
      acc = fmaf(v6, w6, acc);
      acc = fmaf(v7, w7, acc);
    }
  }
  float m = acc;
#pragma unroll
  for (int off = 1; off < 16; off <<= 1) m = fmaxf(m, __shfl_xor(m, off));
  float e = expf(acc - m);
  float ssum = e;
#pragma unroll
  for (int off = 1; off < 16; off <<= 1) ssum += __shfl_xor(ssum, off);
  out[(size_t)node * DIM_OUT + lane] = acc - m - logf(ssum);
}

// ======================= launch =======================

extern "C" void kernel_launch(void* const* d_in, const int* in_sizes, int n_in,
                              void* d_out, int out_size, void* d_ws, size_t ws_size,
                              hipStream_t stream) {
  const float* x  = (const float*)d_in[0];
  const int*   ei = (const int*)d_in[1];
  const float* W1 = (const float*)d_in[2];
  const float* b1 = (const float*)d_in[3];
  const float* W2 = (const float*)d_in[4];
  const float* b2 = (const float*)d_in[5];
  float* out = (float*)d_out;

  const int n = in_sizes[0] / DIM_IN;  // 100000
  const int E = in_sizes[1] / 2;       // 1600000
  const int* srcv = ei;
  const int* dstv = ei + E;
  const int NB = (n + 255) >> NBSHIFT;  // 391

  char* wsb = (char*)d_ws;
  int* degi    = (int*)wsb;   wsb += (size_t)n * 4;
  int* rowptr  = (int*)wsb;   wsb += (size_t)n * 4;
  float* dinv  = (float*)wsb; wsb += (size_t)n * 4;
  int* gbhist  = (int*)wsb;   wsb += 512 * 4;
  int* bbase   = (int*)wsb;   wsb += 512 * 4;
  int* bcursor = (int*)wsb;   wsb += 512 * 4;
  int* srcs    = (int*)wsb;   wsb += (size_t)E * 4;
  ushort* h1   = (ushort*)wsb; wsb += (size_t)n * DIM_H * 2;
  float* agg1  = (float*)wsb;  wsb += (size_t)n * DIM_H * 4;
  ushort* h2   = (ushort*)wsb; wsb += (size_t)n * DIM_OUT * 2;
  // pairs (E int2 = 12.8 MB) aliases agg1 (25.6 MB): dead before k_gather64 writes
  int2* pairs = (int2*)agg1;

  // ---- CSR build ----
  hipMemsetAsync(gbhist, 0, 512 * 4, stream);
  k_bhist<<<256, 256, 0, stream>>>(dstv, E, NB, gbhist);
  k_bscan<<<1, 512, 0, stream>>>(gbhist, NB, bbase, bcursor);
  k_part<<<(E + 8191) / 8192, 256, 0, stream>>>(srcv, dstv, E, NB, bcursor, pairs);
  k_csr<<<NB, 256, 0, stream>>>(pairs, gbhist, bbase, n, degi, dinv, rowptr, srcs);

  // ---- layer 1 ----
  k_gemm1m<<<512, 256, 0, stream>>>(x, W1, h1, n, (n + 15) / 16);
  k_gather64<<<(n + 3) / 4, 256, 0, stream>>>(h1, srcs, rowptr, degi, dinv, b1,
                                              agg1, n);

  // ---- layer 2 ----
  k_gemm2<<<(n + 255) / 256, 256, 0, stream>>>(agg1, W2, h2, n);
  k_gather16<<<(n + 15) / 16, 256, 0, stream>>>(h2, srcs, rowptr, degi, dinv, b2,
                                                out, n);
}

// Round 9
// 163.107 us; speedup vs baseline: 1.3311x; 1.0038x over previous
//
#include <hip/hip_runtime.h>
#include <math.h>

#define DIM_IN 128
#define DIM_H 64
#define DIM_OUT 16
#define NBSHIFT 8  // 256 nodes per bucket

typedef __attribute__((ext_vector_type(8))) short bf16x8;
typedef __attribute__((ext_vector_type(4))) float f32x4;

__device__ __forceinline__ ushort f2bf(float f) {
  uint u = __float_as_uint(f);
  return (ushort)((u + 0x7FFF + ((u >> 16) & 1)) >> 16);
}
__device__ __forceinline__ float bf2f(ushort s) {
  return __uint_as_float(((uint)s) << 16);
}
__device__ __forceinline__ uint cvtpk(float lo, float hi) {
  uint r;
  asm("v_cvt_pk_bf16_f32 %0, %1, %2" : "=v"(r) : "v"(lo), "v"(hi));
  return r;
}

// ======================= bucket histogram =======================
__global__ __launch_bounds__(256) void k_bhist(const int* __restrict__ dst, int E,
                                               int NB, int* __restrict__ gbhist) {
  __shared__ int lh[512];
  int t = threadIdx.x;
  lh[t] = 0;
  lh[t + 256] = 0;
  __syncthreads();
  for (int i = blockIdx.x * 256 + t; i < E; i += gridDim.x * 256)
    atomicAdd(&lh[dst[i] >> NBSHIFT], 1);
  __syncthreads();
  for (int b = t; b < NB; b += 256) {
    int c = lh[b];
    if (c) atomicAdd(&gbhist[b], c);
  }
}

// exclusive scan of gbhist[NB] -> bbase, bcursor (NB <= 512), single block
__global__ __launch_bounds__(512) void k_bscan(const int* __restrict__ gbhist, int NB,
                                               int* __restrict__ bbase,
                                               int* __restrict__ bcursor) {
  __shared__ int sb[512];
  int t = threadIdx.x;
  int v = (t < NB) ? gbhist[t] : 0;
  sb[t] = v;
  __syncthreads();
  for (int off = 1; off < 512; off <<= 1) {
    int add = (t >= off) ? sb[t - off] : 0;
    __syncthreads();
    sb[t] += add;
    __syncthreads();
  }
  if (t < NB) {
    int e = sb[t] - v;
    bbase[t] = e;
    bcursor[t] = e;
  }
}

// ======================= partition into bucket regions =======================
// pairs packed: (src << 8) | (dst & 255)   [src < 2^24, dst-in-bucket 8 bits]
__global__ __launch_bounds__(256) void k_part(const int* __restrict__ src,
                                              const int* __restrict__ dst, int E,
                                              int NB, int* __restrict__ bcursor,
                                              uint* __restrict__ pairs) {
  __shared__ int lh[512];
  __shared__ int lcur[512];
  int t = threadIdx.x;
  lh[t] = 0;
  lh[t + 256] = 0;
  __syncthreads();
  int e0 = blockIdx.x * 8192;
  int e1 = min(E, e0 + 8192);
  for (int i = e0 + t; i < e1; i += 256) atomicAdd(&lh[dst[i] >> NBSHIFT], 1);
  __syncthreads();
  for (int b = t; b < NB; b += 256) {
    int c = lh[b];
    lcur[b] = c ? atomicAdd(&bcursor[b], c) : 0;
  }
  __syncthreads();
  for (int i = e0 + t; i < e1; i += 256) {
    int d = dst[i];
    int pos = atomicAdd(&lcur[d >> NBSHIFT], 1);
    pairs[pos] = ((uint)src[i] << 8) | ((uint)d & 255u);
  }
}

// ======================= per-bucket CSR + deg + dinv ==============
__global__ __launch_bounds__(256) void k_csr(const uint* __restrict__ pairs,
                                             const int* __restrict__ gbhist,
                                             const int* __restrict__ bbase, int n,
                                             int* __restrict__ degi,
                                             float* __restrict__ dinv,
                                             int* __restrict__ rowptr,
                                             int* __restrict__ srcs) {
  __shared__ int nh[256];
  __shared__ int ncur[256];
  int t = threadIdx.x;
  int b = blockIdx.x;
  int base = bbase[b];
  int cnt = gbhist[b];
  nh[t] = 0;
  __syncthreads();
  for (int i = t; i < cnt; i += 256) atomicAdd(&nh[pairs[base + i] & 255u], 1);
  __syncthreads();
  int node = (b << NBSHIFT) + t;
  int v = nh[t];
  if (node < n) {
    degi[node] = v;
    dinv[node] = rsqrtf((float)v + 1.0f);
  }
  __syncthreads();
  for (int off = 1; off < 256; off <<= 1) {
    int add = (t >= off) ? nh[t - off] : 0;
    __syncthreads();
    nh[t] += add;
    __syncthreads();
  }
  int excl = nh[t] - v;
  if (node < n) rowptr[node] = base + excl;
  ncur[t] = base + excl;
  __syncthreads();
  for (int i = t; i < cnt; i += 256) {
    uint p = pairs[base + i];
    int pos = atomicAdd(&ncur[p & 255u], 1);
    srcs[pos] = (int)(p >> 8);
  }
}

// ======================= GEMM1 (MFMA bf16): h1 = x @ W1 =======================
__global__ __launch_bounds__(256, 4) void k_gemm1m(const float* __restrict__ x,
                                                   const float* __restrict__ W,
                                                   ushort* __restrict__ h, int n,
                                                   int nTiles) {
  const int t = threadIdx.x;
  const int lane = t & 63;
  const int wid = blockIdx.x * 4 + (t >> 6);
  const int nW = gridDim.x * 4;
  const int cc = lane & 15;        // A row offset / B,D col offset
  const int kb = (lane >> 4) * 8;  // k-octet within 32-chunk

  bf16x8 bfrag[4][4];
#pragma unroll
  for (int kc = 0; kc < 4; ++kc)
#pragma unroll
    for (int nt = 0; nt < 4; ++nt) {
      union { bf16x8 v; uint u[4]; } fb;
#pragma unroll
      for (int j = 0; j < 4; ++j) {
        float lo = W[(size_t)(kc * 32 + kb + 2 * j) * DIM_H + nt * 16 + cc];
        float hi = W[(size_t)(kc * 32 + kb + 2 * j + 1) * DIM_H + nt * 16 + cc];
        fb.u[j] = cvtpk(lo, hi);
      }
      bfrag[kc][nt] = fb.v;
    }

  for (int tile = wid; tile < nTiles; tile += nW) {
    int row0 = tile * 16;
    int ra = row0 + cc;
    if (ra > n - 1) ra = n - 1;
    const float* xp = x + (size_t)ra * DIM_IN;
    f32x4 acc[4] = {{0.f, 0.f, 0.f, 0.f},
                    {0.f, 0.f, 0.f, 0.f},
                    {0.f, 0.f, 0.f, 0.f},
                    {0.f, 0.f, 0.f, 0.f}};
#pragma unroll
    for (int kc = 0; kc < 4; ++kc) {
      float4 a0 = *(const float4*)(xp + kc * 32 + kb);
      float4 a1 = *(const float4*)(xp + kc * 32 + kb + 4);
      union { bf16x8 v; uint u[4]; } fa;
      fa.u[0] = cvtpk(a0.x, a0.y);
      fa.u[1] = cvtpk(a0.z, a0.w);
      fa.u[2] = cvtpk(a1.x, a1.y);
      fa.u[3] = cvtpk(a1.z, a1.w);
#pragma unroll
      for (int nt = 0; nt < 4; ++nt)
        acc[nt] = __builtin_amdgcn_mfma_f32_16x16x32_bf16(fa.v, bfrag[kc][nt],
                                                          acc[nt], 0, 0, 0);
    }
    int rbase = row0 + (lane >> 4) * 4;
#pragma unroll
    for (int nt = 0; nt < 4; ++nt) {
      int col = nt * 16 + cc;
#pragma unroll
      for (int j = 0; j < 4; ++j) {
        int r = rbase + j;
        if (r < n) h[(size_t)r * DIM_H + col] = f2bf(acc[nt][j]);
      }
    }
  }
}

// ============ GEMM2: h2(bf16) = relu(agg1:bf16) @ W2 ============
__global__ __launch_bounds__(256) void k_gemm2(const ushort* __restrict__ a,
                                               const float* __restrict__ W,
                                               ushort* __restrict__ h2, int n) {
  __shared__ float Ws[64][16];
  const int t = threadIdx.x;
  for (int i = t; i < 64 * 16; i += 256) Ws[i >> 4][i & 15] = W[i];
  __syncthreads();
  int r = blockIdx.x * 256 + t;
  if (r >= n) return;
  const uint4* ap = (const uint4*)(a + (size_t)r * DIM_H);
  float acc[16] = {};
#pragma unroll
  for (int k8 = 0; k8 < 8; ++k8) {
    uint4 v = ap[k8];
    uint w[4] = {v.x, v.y, v.z, v.w};
#pragma unroll
    for (int p = 0; p < 4; ++p) {
      float v0 = fmaxf(bf2f((ushort)(w[p] & 0xffff)), 0.f);
      float v1 = fmaxf(bf2f((ushort)(w[p] >> 16)), 0.f);
      int k = k8 * 8 + p * 2;
#pragma unroll
      for (int j = 0; j < 16; ++j) acc[j] = fmaf(v0, Ws[k][j], acc[j]);
#pragma unroll
      for (int j = 0; j < 16; ++j) acc[j] = fmaf(v1, Ws[k + 1][j], acc[j]);
    }
  }
  ushort4* hp = (ushort4*)(h2 + (size_t)r * DIM_OUT);
#pragma unroll
  for (int q = 0; q < 4; ++q) {
    ushort4 o;
    o.x = f2bf(acc[q * 4 + 0]);
    o.y = f2bf(acc[q * 4 + 1]);
    o.z = f2bf(acc[q * 4 + 2]);
    o.w = f2bf(acc[q * 4 + 3]);
    hp[q] = o;
  }
}

// ======================= gather aggregation =======================

// layer 1: one wave per node. q=lane&15 owns cols 4q..4q+3 (uint2 = 4 bf16),
// g=lane>>4 processes edges j+g and j+4+g (bpermute index). Cross-group
// shfl_xor(16/32) reduce; agg written as bf16.
__global__ __launch_bounds__(256) void k_gather64(const ushort* __restrict__ h,
                                                  const int* __restrict__ srcs,
                                                  const int* __restrict__ rowptr,
                                                  const int* __restrict__ deg,
                                                  const float* __restrict__ dinv,
                                                  const float* __restrict__ b,
                                                  ushort* __restrict__ out, int n) {
  int node = blockIdx.x * 4 + (threadIdx.x >> 6);
  int lane = threadIdx.x & 63;
  int g = lane >> 4;
  int q = lane & 15;
  if (node >= n) return;
  int start = rowptr[node];
  int cnt = deg[node];
  float dd = dinv[node];
  float a0 = 0.f, a1 = 0.f, a2 = 0.f, a3 = 0.f;
  for (int j0 = 0; j0 < cnt; j0 += 64) {
    int rem = cnt - j0;
    if (rem > 64) rem = 64;
    int s_l = (lane < rem) ? srcs[start + j0 + lane] : 0;
    float w_l = (lane < rem) ? dinv[s_l] * dd : 0.0f;
    for (int j = 0; j < rem; j += 8) {
      int iA = j + g;       // <= 59
      int iB = j + 4 + g;   // <= 63
      int sA = __shfl(s_l, iA);
      float wA = __shfl(w_l, iA);
      int sB = __shfl(s_l, iB);
      float wB = __shfl(w_l, iB);
      uint2 vA = *(const uint2*)(h + (size_t)sA * DIM_H + q * 4);
      uint2 vB = *(const uint2*)(h + (size_t)sB * DIM_H + q * 4);
      a0 = fmaf(bf2f((ushort)(vA.x & 0xffff)), wA, a0);
      a1 = fmaf(bf2f((ushort)(vA.x >> 16)), wA, a1);
      a2 = fmaf(bf2f((ushort)(vA.y & 0xffff)), wA, a2);
      a3 = fmaf(bf2f((ushort)(vA.y >> 16)), wA, a3);
      a0 = fmaf(bf2f((ushort)(vB.x & 0xffff)), wB, a0);
      a1 = fmaf(bf2f((ushort)(vB.x >> 16)), wB, a1);
      a2 = fmaf(bf2f((ushort)(vB.y & 0xffff)), wB, a2);
      a3 = fmaf(bf2f((ushort)(vB.y >> 16)), wB, a3);
    }
  }
  // sum across the 4 edge-groups
  a0 += __shfl_xor(a0, 16); a0 += __shfl_xor(a0, 32);
  a1 += __shfl_xor(a1, 16); a1 += __shfl_xor(a1, 32);
  a2 += __shfl_xor(a2, 16); a2 += __shfl_xor(a2, 32);
  a3 += __shfl_xor(a3, 16); a3 += __shfl_xor(a3, 32);
  if (g == 0) {
    uint2 sv = *(const uint2*)(h + (size_t)node * DIM_H + q * 4);
    float s2 = dd * dd;
    a0 = fmaf(bf2f((ushort)(sv.x & 0xffff)), s2, a0) + b[4 * q + 0];
    a1 = fmaf(bf2f((ushort)(sv.x >> 16)), s2, a1) + b[4 * q + 1];
    a2 = fmaf(bf2f((ushort)(sv.y & 0xffff)), s2, a2) + b[4 * q + 2];
    a3 = fmaf(bf2f((ushort)(sv.y >> 16)), s2, a3) + b[4 * q + 3];
    uint lo = cvtpk(a0, a1);
    uint hi = cvtpk(a2, a3);
    *(uint2*)(out + (size_t)node * DIM_H + q * 4) = make_uint2(lo, hi);
  }
}

// layer 2: 16 lanes per node: c=lane&3 owns cols 4c..4c+3 (uint2), e=(lane>>2)&3
// is the edge subgroup; fused self+bias+log_softmax. out f32.
__global__ __launch_bounds__(256) void k_gather16(const ushort* __restrict__ h,
                                                  const int* __restrict__ srcs,
                                                  const int* __restrict__ rowptr,
                                                  const int* __restrict__ deg,
                                                  const float* __restrict__ dinv,
                                                  const float* __restrict__ b,
                                                  float* __restrict__ out, int n) {
  int node = blockIdx.x * 16 + (threadIdx.x >> 4);
  int lane = threadIdx.x & 63;
  int lane16 = lane & 15;
  int gbase = lane & 48;       // base lane of this node's 16-lane group
  int e = (lane >> 2) & 3;     // edge subgroup
  int c = lane & 3;            // col quad
  if (node >= n) return;
  int start = rowptr[node];
  int cnt = deg[node];
  float dd = dinv[node];
  float a0 = 0.f, a1 = 0.f, a2 = 0.f, a3 = 0.f;
  for (int j0 = 0; j0 < cnt; j0 += 16) {
    int rem = cnt - j0;
    if (rem > 16) rem = 16;
    int s_l = (lane16 < rem) ? srcs[start + j0 + lane16] : 0;
    float w_l = (lane16 < rem) ? dinv[s_l] * dd : 0.0f;
    for (int j = 0; j < rem; j += 8) {
      int iA = gbase + j + e;
      int iB = gbase + j + 4 + e;
      int sA = __shfl(s_l, iA);
      float wA = __shfl(w_l, iA);
      int sB = __shfl(s_l, iB);
      float wB = __shfl(w_l, iB);
      uint2 vA = *(const uint2*)(h + (size_t)sA * DIM_OUT + c * 4);
      uint2 vB = *(const uint2*)(h + (size_t)sB * DIM_OUT + c * 4);
      a0 = fmaf(bf2f((ushort)(vA.x & 0xffff)), wA, a0);
      a1 = fmaf(bf2f((ushort)(vA.x >> 16)), wA, a1);
      a2 = fmaf(bf2f((ushort)(vA.y & 0xffff)), wA, a2);
      a3 = fmaf(bf2f((ushort)(vA.y >> 16)), wA, a3);
      a0 = fmaf(bf2f((ushort)(vB.x & 0xffff)), wB, a0);
      a1 = fmaf(bf2f((ushort)(vB.x >> 16)), wB, a1);
      a2 = fmaf(bf2f((ushort)(vB.y & 0xffff)), wB, a2);
      a3 = fmaf(bf2f((ushort)(vB.y >> 16)), wB, a3);
    }
  }
  // reduce across edge subgroups (lane bits 2,3)
  a0 += __shfl_xor(a0, 4); a0 += __shfl_xor(a0, 8);
  a1 += __shfl_xor(a1, 4); a1 += __shfl_xor(a1, 8);
  a2 += __shfl_xor(a2, 4); a2 += __shfl_xor(a2, 8);
  a3 += __shfl_xor(a3, 4); a3 += __shfl_xor(a3, 8);
  // self-loop + bias
  uint2 sv = *(const uint2*)(h + (size_t)node * DIM_OUT + c * 4);
  float s2 = dd * dd;
  a0 = fmaf(bf2f((ushort)(sv.x & 0xffff)), s2, a0) + b[4 * c + 0];
  a1 = fmaf(bf2f((ushort)(sv.x >> 16)), s2, a1) + b[4 * c + 1];
  a2 = fmaf(bf2f((ushort)(sv.y & 0xffff)), s2, a2) + b[4 * c + 2];
  a3 = fmaf(bf2f((ushort)(sv.y >> 16)), s2, a3) + b[4 * c + 3];
  // log_softmax over 16 cols: in-lane 4 + cross-lane (bits 0,1)
  float m = fmaxf(fmaxf(a0, a1), fmaxf(a2, a3));
  m = fmaxf(m, __shfl_xor(m, 1));
  m = fmaxf(m, __shfl_xor(m, 2));
  float ssum = expf(a0 - m) + expf(a1 - m) + expf(a2 - m) + expf(a3 - m);
  ssum += __shfl_xor(ssum, 1);
  ssum += __shfl_xor(ssum, 2);
  float l = m + logf(ssum);
  if (e == 0)
    *(float4*)(out + (size_t)node * DIM_OUT + c * 4) =
        make_float4(a0 - l, a1 - l, a2 - l, a3 - l);
}

// ======================= launch =======================

extern "C" void kernel_launch(void* const* d_in, const int* in_sizes, int n_in,
                              void* d_out, int out_size, void* d_ws, size_t ws_size,
                              hipStream_t stream) {
  const float* x  = (const float*)d_in[0];
  const int*   ei = (const int*)d_in[1];
  const float* W1 = (const float*)d_in[2];
  const float* b1 = (const float*)d_in[3];
  const float* W2 = (const float*)d_in[4];
  const float* b2 = (const float*)d_in[5];
  float* out = (float*)d_out;

  const int n = in_sizes[0] / DIM_IN;  // 100000
  const int E = in_sizes[1] / 2;       // 1600000
  const int* srcv = ei;
  const int* dstv = ei + E;
  const int NB = (n + 255) >> NBSHIFT;  // 391

  char* wsb = (char*)d_ws;
  int* degi    = (int*)wsb;   wsb += (size_t)n * 4;
  int* rowptr  = (int*)wsb;   wsb += (size_t)n * 4;
  float* dinv  = (float*)wsb; wsb += (size_t)n * 4;
  int* gbhist  = (int*)wsb;   wsb += 512 * 4;
  int* bbase   = (int*)wsb;   wsb += 512 * 4;
  int* bcursor = (int*)wsb;   wsb += 512 * 4;
  int* srcs    = (int*)wsb;   wsb += (size_t)E * 4;
  ushort* h1   = (ushort*)wsb; wsb += (size_t)n * DIM_H * 2;
  ushort* agg1 = (ushort*)wsb; wsb += (size_t)n * DIM_H * 2;
  ushort* h2   = (ushort*)wsb; wsb += (size_t)n * DIM_OUT * 2;
  // pairs (E uint = 6.4 MB) aliases agg1 (12.8 MB): dead before k_gather64 writes
  uint* pairs = (uint*)agg1;

  // ---- CSR build ----
  hipMemsetAsync(gbhist, 0, 512 * 4, stream);
  k_bhist<<<256, 256, 0, stream>>>(dstv, E, NB, gbhist);
  k_bscan<<<1, 512, 0, stream>>>(gbhist, NB, bbase, bcursor);
  k_part<<<(E + 8191) / 8192, 256, 0, stream>>>(srcv, dstv, E, NB, bcursor, pairs);
  k_csr<<<NB, 256, 0, stream>>>(pairs, gbhist, bbase, n, degi, dinv, rowptr, srcs);

  // ---- layer 1 ----
  k_gemm1m<<<512, 256, 0, stream>>>(x, W1, h1, n, (n + 15) / 16);
  k_gather64<<<(n + 3) / 4, 256, 0, stream>>>(h1, srcs, rowptr, degi, dinv, b1,
                                              agg1, n);

  // ---- layer 2 ----
  k_gemm2<<<(n + 255) / 256, 256, 0, stream>>>(agg1, W2, h2, n);
  k_gather16<<<(n + 15) / 16, 256, 0, stream>>>(h2, srcs, rowptr, degi, dinv, b2,
                                                out, n);
}

// Round 10
// 148.517 us; speedup vs baseline: 1.4618x; 1.0982x over previous
//
#include <hip/hip_runtime.h>
#include <math.h>

#define DIM_IN 128
#define DIM_H 64
#define DIM_OUT 16
#define NBSHIFT 8  // 256 nodes per bucket
#define CHUNK 8192

typedef __attribute__((ext_vector_type(8))) short bf16x8;
typedef __attribute__((ext_vector_type(4))) float f32x4;

__device__ __forceinline__ ushort f2bf(float f) {
  uint u = __float_as_uint(f);
  return (ushort)((u + 0x7FFF + ((u >> 16) & 1)) >> 16);
}
__device__ __forceinline__ float bf2f(ushort s) {
  return __uint_as_float(((uint)s) << 16);
}
__device__ __forceinline__ uint cvtpk(float lo, float hi) {
  uint r;
  asm("v_cvt_pk_bf16_f32 %0, %1, %2" : "=v"(r) : "v"(lo), "v"(hi));
  return r;
}

// ============ CSR build: per-chunk hist -> scans -> partition (atomic-free) ====

// per-chunk bucket histogram; writes all 512 slots (no memset needed)
__global__ __launch_bounds__(256) void k_hist1(const int* __restrict__ dst, int E,
                                               int* __restrict__ chunkhist) {
  __shared__ int lh[512];
  int t = threadIdx.x;
  int c = blockIdx.x;
  lh[t] = 0;
  lh[t + 256] = 0;
  __syncthreads();
  int e0 = c * CHUNK;
  int e1 = min(E, e0 + CHUNK);
  for (int i = e0 + t; i < e1; i += 256) atomicAdd(&lh[dst[i] >> NBSHIFT], 1);
  __syncthreads();
  chunkhist[c * 512 + t] = lh[t];
  chunkhist[c * 512 + t + 256] = lh[t + 256];
}

// per-bucket exclusive scan across chunks (block b handles bucket b; NC<=256)
__global__ __launch_bounds__(256) void k_scanc(const int* __restrict__ chunkhist,
                                               int NC, int* __restrict__ cstart,
                                               int* __restrict__ gbhist) {
  __shared__ int sc[256];
  int t = threadIdx.x;
  int b = blockIdx.x;
  int v = (t < NC) ? chunkhist[t * 512 + b] : 0;
  sc[t] = v;
  __syncthreads();
  for (int off = 1; off < 256; off <<= 1) {
    int add = (t >= off) ? sc[t - off] : 0;
    __syncthreads();
    sc[t] += add;
    __syncthreads();
  }
  if (t < NC) cstart[t * 512 + b] = sc[t] - v;
  if (t == 255) gbhist[b] = sc[255];
}

// exclusive scan of gbhist[512] -> bbase (single block)
__global__ __launch_bounds__(512) void k_bscan(const int* __restrict__ gbhist,
                                               int* __restrict__ bbase) {
  __shared__ int sb[512];
  int t = threadIdx.x;
  int v = gbhist[t];
  sb[t] = v;
  __syncthreads();
  for (int off = 1; off < 512; off <<= 1) {
    int add = (t >= off) ? sb[t - off] : 0;
    __syncthreads();
    sb[t] += add;
    __syncthreads();
  }
  bbase[t] = sb[t] - v;
}

// partition into bucket regions; cursors from cstart+bbase (no global atomics)
// pairs packed: (src << 8) | (dst & 255)
__global__ __launch_bounds__(256) void k_part2(const int* __restrict__ src,
                                               const int* __restrict__ dst, int E,
                                               const int* __restrict__ cstart,
                                               const int* __restrict__ bbase,
                                               uint* __restrict__ pairs) {
  __shared__ int lcur[512];
  int t = threadIdx.x;
  int c = blockIdx.x;
  lcur[t] = cstart[c * 512 + t] + bbase[t];
  lcur[t + 256] = cstart[c * 512 + t + 256] + bbase[t + 256];
  __syncthreads();
  int e0 = c * CHUNK;
  int e1 = min(E, e0 + CHUNK);
  for (int i = e0 + t; i < e1; i += 256) {
    int d = dst[i];
    int pos = atomicAdd(&lcur[d >> NBSHIFT], 1);
    pairs[pos] = ((uint)src[i] << 8) | ((uint)d & 255u);
  }
}

// per-bucket CSR + deg + dinv
__global__ __launch_bounds__(256) void k_csr(const uint* __restrict__ pairs,
                                             const int* __restrict__ gbhist,
                                             const int* __restrict__ bbase, int n,
                                             int* __restrict__ degi,
                                             float* __restrict__ dinv,
                                             int* __restrict__ rowptr,
                                             int* __restrict__ srcs) {
  __shared__ int nh[256];
  __shared__ int ncur[256];
  int t = threadIdx.x;
  int b = blockIdx.x;
  int base = bbase[b];
  int cnt = gbhist[b];
  nh[t] = 0;
  __syncthreads();
  for (int i = t; i < cnt; i += 256) atomicAdd(&nh[pairs[base + i] & 255u], 1);
  __syncthreads();
  int node = (b << NBSHIFT) + t;
  int v = nh[t];
  if (node < n) {
    degi[node] = v;
    dinv[node] = rsqrtf((float)v + 1.0f);
  }
  __syncthreads();
  for (int off = 1; off < 256; off <<= 1) {
    int add = (t >= off) ? nh[t - off] : 0;
    __syncthreads();
    nh[t] += add;
    __syncthreads();
  }
  int excl = nh[t] - v;
  if (node < n) rowptr[node] = base + excl;
  ncur[t] = base + excl;
  __syncthreads();
  for (int i = t; i < cnt; i += 256) {
    uint p = pairs[base + i];
    int pos = atomicAdd(&ncur[p & 255u], 1);
    srcs[pos] = (int)(p >> 8);
  }
}

// wedge[i] = bf16(dinv[srcs[i]]) -- moves the random dinv gather off the
// gathers' critical path (they read it coalesced alongside srcs).
__global__ __launch_bounds__(256) void k_wedge(const int* __restrict__ srcs,
                                               const float* __restrict__ dinv,
                                               ushort* __restrict__ wedge, int E) {
  int i = blockIdx.x * 256 + threadIdx.x;
  if (i < E) wedge[i] = f2bf(dinv[srcs[i]]);
}

// ======================= GEMM1 (MFMA bf16): h1 = x @ W1 =======================
__global__ __launch_bounds__(256, 4) void k_gemm1m(const float* __restrict__ x,
                                                   const float* __restrict__ W,
                                                   ushort* __restrict__ h, int n,
                                                   int nTiles) {
  const int t = threadIdx.x;
  const int lane = t & 63;
  const int wid = blockIdx.x * 4 + (t >> 6);
  const int nW = gridDim.x * 4;
  const int cc = lane & 15;        // A row offset / B,D col offset
  const int kb = (lane >> 4) * 8;  // k-octet within 32-chunk

  bf16x8 bfrag[4][4];
#pragma unroll
  for (int kc = 0; kc < 4; ++kc)
#pragma unroll
    for (int nt = 0; nt < 4; ++nt) {
      union { bf16x8 v; uint u[4]; } fb;
#pragma unroll
      for (int j = 0; j < 4; ++j) {
        float lo = W[(size_t)(kc * 32 + kb + 2 * j) * DIM_H + nt * 16 + cc];
        float hi = W[(size_t)(kc * 32 + kb + 2 * j + 1) * DIM_H + nt * 16 + cc];
        fb.u[j] = cvtpk(lo, hi);
      }
      bfrag[kc][nt] = fb.v;
    }

  for (int tile = wid; tile < nTiles; tile += nW) {
    int row0 = tile * 16;
    int ra = row0 + cc;
    if (ra > n - 1) ra = n - 1;
    const float* xp = x + (size_t)ra * DIM_IN;
    f32x4 acc[4] = {{0.f, 0.f, 0.f, 0.f},
                    {0.f, 0.f, 0.f, 0.f},
                    {0.f, 0.f, 0.f, 0.f},
                    {0.f, 0.f, 0.f, 0.f}};
#pragma unroll
    for (int kc = 0; kc < 4; ++kc) {
      float4 a0 = *(const float4*)(xp + kc * 32 + kb);
      float4 a1 = *(const float4*)(xp + kc * 32 + kb + 4);
      union { bf16x8 v; uint u[4]; } fa;
      fa.u[0] = cvtpk(a0.x, a0.y);
      fa.u[1] = cvtpk(a0.z, a0.w);
      fa.u[2] = cvtpk(a1.x, a1.y);
      fa.u[3] = cvtpk(a1.z, a1.w);
#pragma unroll
      for (int nt = 0; nt < 4; ++nt)
        acc[nt] = __builtin_amdgcn_mfma_f32_16x16x32_bf16(fa.v, bfrag[kc][nt],
                                                          acc[nt], 0, 0, 0);
    }
    int rbase = row0 + (lane >> 4) * 4;
#pragma unroll
    for (int nt = 0; nt < 4; ++nt) {
      int col = nt * 16 + cc;
#pragma unroll
      for (int j = 0; j < 4; ++j) {
        int r = rbase + j;
        if (r < n) h[(size_t)r * DIM_H + col] = f2bf(acc[nt][j]);
      }
    }
  }
}

// ============ GEMM2: h2(bf16) = relu(agg1:bf16) @ W2 ============
__global__ __launch_bounds__(256) void k_gemm2(const ushort* __restrict__ a,
                                               const float* __restrict__ W,
                                               ushort* __restrict__ h2, int n) {
  __shared__ float Ws[64][16];
  const int t = threadIdx.x;
  for (int i = t; i < 64 * 16; i += 256) Ws[i >> 4][i & 15] = W[i];
  __syncthreads();
  int r = blockIdx.x * 256 + t;
  if (r >= n) return;
  const uint4* ap = (const uint4*)(a + (size_t)r * DIM_H);
  float acc[16] = {};
#pragma unroll
  for (int k8 = 0; k8 < 8; ++k8) {
    uint4 v = ap[k8];
    uint w[4] = {v.x, v.y, v.z, v.w};
#pragma unroll
    for (int p = 0; p < 4; ++p) {
      float v0 = fmaxf(bf2f((ushort)(w[p] & 0xffff)), 0.f);
      float v1 = fmaxf(bf2f((ushort)(w[p] >> 16)), 0.f);
      int k = k8 * 8 + p * 2;
#pragma unroll
      for (int j = 0; j < 16; ++j) acc[j] = fmaf(v0, Ws[k][j], acc[j]);
#pragma unroll
      for (int j = 0; j < 16; ++j) acc[j] = fmaf(v1, Ws[k + 1][j], acc[j]);
    }
  }
  ushort4* hp = (ushort4*)(h2 + (size_t)r * DIM_OUT);
#pragma unroll
  for (int q = 0; q < 4; ++q) {
    ushort4 o;
    o.x = f2bf(acc[q * 4 + 0]);
    o.y = f2bf(acc[q * 4 + 1]);
    o.z = f2bf(acc[q * 4 + 2]);
    o.w = f2bf(acc[q * 4 + 3]);
    hp[q] = o;
  }
}

// ======================= gather aggregation =======================

// layer 1: one wave per node. q=lane&15 owns cols 4q..4q+3 (uint2), g=lane>>4
// processes edges j+g, j+4+g, j+8+g, j+12+g (4 loads in flight). Weights come
// coalesced from wedge (bf16 dinv[src]) * dd.
__global__ __launch_bounds__(256) void k_gather64(const ushort* __restrict__ h,
                                                  const int* __restrict__ srcs,
                                                  const ushort* __restrict__ wedge,
                                                  const int* __restrict__ rowptr,
                                                  const int* __restrict__ deg,
                                                  const float* __restrict__ dinv,
                                                  const float* __restrict__ b,
                                                  ushort* __restrict__ out, int n) {
  int node = blockIdx.x * 4 + (threadIdx.x >> 6);
  int lane = threadIdx.x & 63;
  int g = lane >> 4;
  int q = lane & 15;
  if (node >= n) return;
  int start = rowptr[node];
  int cnt = deg[node];
  float dd = dinv[node];
  float a0 = 0.f, a1 = 0.f, a2 = 0.f, a3 = 0.f;
  for (int j0 = 0; j0 < cnt; j0 += 64) {
    int rem = cnt - j0;
    if (rem > 64) rem = 64;
    int s_l = (lane < rem) ? srcs[start + j0 + lane] : 0;
    float w_l = (lane < rem) ? bf2f(wedge[start + j0 + lane]) * dd : 0.0f;
    for (int j = 0; j < rem; j += 16) {
      int i0 = j + g, i1 = j + 4 + g, i2 = j + 8 + g, i3 = j + 12 + g;  // <= 63
      int s0 = __shfl(s_l, i0);
      float w0 = __shfl(w_l, i0);
      int s1 = __shfl(s_l, i1);
      float w1 = __shfl(w_l, i1);
      int s2 = __shfl(s_l, i2);
      float w2 = __shfl(w_l, i2);
      int s3 = __shfl(s_l, i3);
      float w3 = __shfl(w_l, i3);
      uint2 v0 = *(const uint2*)(h + (size_t)s0 * DIM_H + q * 4);
      uint2 v1 = *(const uint2*)(h + (size_t)s1 * DIM_H + q * 4);
      uint2 v2 = *(const uint2*)(h + (size_t)s2 * DIM_H + q * 4);
      uint2 v3 = *(const uint2*)(h + (size_t)s3 * DIM_H + q * 4);
      a0 = fmaf(bf2f((ushort)(v0.x & 0xffff)), w0, a0);
      a1 = fmaf(bf2f((ushort)(v0.x >> 16)), w0, a1);
      a2 = fmaf(bf2f((ushort)(v0.y & 0xffff)), w0, a2);
      a3 = fmaf(bf2f((ushort)(v0.y >> 16)), w0, a3);
      a0 = fmaf(bf2f((ushort)(v1.x & 0xffff)), w1, a0);
      a1 = fmaf(bf2f((ushort)(v1.x >> 16)), w1, a1);
      a2 = fmaf(bf2f((ushort)(v1.y & 0xffff)), w1, a2);
      a3 = fmaf(bf2f((ushort)(v1.y >> 16)), w1, a3);
      a0 = fmaf(bf2f((ushort)(v2.x & 0xffff)), w2, a0);
      a1 = fmaf(bf2f((ushort)(v2.x >> 16)), w2, a1);
      a2 = fmaf(bf2f((ushort)(v2.y & 0xffff)), w2, a2);
      a3 = fmaf(bf2f((ushort)(v2.y >> 16)), w2, a3);
      a0 = fmaf(bf2f((ushort)(v3.x & 0xffff)), w3, a0);
      a1 = fmaf(bf2f((ushort)(v3.x >> 16)), w3, a1);
      a2 = fmaf(bf2f((ushort)(v3.y & 0xffff)), w3, a2);
      a3 = fmaf(bf2f((ushort)(v3.y >> 16)), w3, a3);
    }
  }
  a0 += __shfl_xor(a0, 16); a0 += __shfl_xor(a0, 32);
  a1 += __shfl_xor(a1, 16); a1 += __shfl_xor(a1, 32);
  a2 += __shfl_xor(a2, 16); a2 += __shfl_xor(a2, 32);
  a3 += __shfl_xor(a3, 16); a3 += __shfl_xor(a3, 32);
  if (g == 0) {
    uint2 sv = *(const uint2*)(h + (size_t)node * DIM_H + q * 4);
    float s2 = dd * dd;
    a0 = fmaf(bf2f((ushort)(sv.x & 0xffff)), s2, a0) + b[4 * q + 0];
    a1 = fmaf(bf2f((ushort)(sv.x >> 16)), s2, a1) + b[4 * q + 1];
    a2 = fmaf(bf2f((ushort)(sv.y & 0xffff)), s2, a2) + b[4 * q + 2];
    a3 = fmaf(bf2f((ushort)(sv.y >> 16)), s2, a3) + b[4 * q + 3];
    uint lo = cvtpk(a0, a1);
    uint hi = cvtpk(a2, a3);
    *(uint2*)(out + (size_t)node * DIM_H + q * 4) = make_uint2(lo, hi);
  }
}

// layer 2: 16 lanes per node; c=lane&3 owns cols 4c..4c+3, e=(lane>>2)&3 picks
// edges e, 4+e, 8+e, 12+e of each 16-chunk (4 loads in flight, wave-constant
// shfl indices). Fused self+bias+log_softmax. out f32.
__global__ __launch_bounds__(256) void k_gather16(const ushort* __restrict__ h,
                                                  const int* __restrict__ srcs,
                                                  const ushort* __restrict__ wedge,
                                                  const int* __restrict__ rowptr,
                                                  const int* __restrict__ deg,
                                                  const float* __restrict__ dinv,
                                                  const float* __restrict__ b,
                                                  float* __restrict__ out, int n) {
  int node = blockIdx.x * 16 + (threadIdx.x >> 4);
  int lane = threadIdx.x & 63;
  int lane16 = lane & 15;
  int gbase = lane & 48;
  int e = (lane >> 2) & 3;
  int c = lane & 3;
  if (node >= n) return;
  int start = rowptr[node];
  int cnt = deg[node];
  float dd = dinv[node];
  const int iA = gbase + e, iB = gbase + 4 + e, iC = gbase + 8 + e,
            iD = gbase + 12 + e;
  float a0 = 0.f, a1 = 0.f, a2 = 0.f, a3 = 0.f;
  for (int j0 = 0; j0 < cnt; j0 += 16) {
    int rem = cnt - j0;
    if (rem > 16) rem = 16;
    int s_l = (lane16 < rem) ? srcs[start + j0 + lane16] : 0;
    float w_l = (lane16 < rem) ? bf2f(wedge[start + j0 + lane16]) * dd : 0.0f;
    int sA = __shfl(s_l, iA);
    float wA = __shfl(w_l, iA);
    int sB = __shfl(s_l, iB);
    float wB = __shfl(w_l, iB);
    int sC = __shfl(s_l, iC);
    float wC = __shfl(w_l, iC);
    int sD = __shfl(s_l, iD);
    float wD = __shfl(w_l, iD);
    uint2 vA = *(const uint2*)(h + (size_t)sA * DIM_OUT + c * 4);
    uint2 vB = *(const uint2*)(h + (size_t)sB * DIM_OUT + c * 4);
    uint2 vC = *(const uint2*)(h + (size_t)sC * DIM_OUT + c * 4);
    uint2 vD = *(const uint2*)(h + (size_t)sD * DIM_OUT + c * 4);
    a0 = fmaf(bf2f((ushort)(vA.x & 0xffff)), wA, a0);
    a1 = fmaf(bf2f((ushort)(vA.x >> 16)), wA, a1);
    a2 = fmaf(bf2f((ushort)(vA.y & 0xffff)), wA, a2);
    a3 = fmaf(bf2f((ushort)(vA.y >> 16)), wA, a3);
    a0 = fmaf(bf2f((ushort)(vB.x & 0xffff)), wB, a0);
    a1 = fmaf(bf2f((ushort)(vB.x >> 16)), wB, a1);
    a2 = fmaf(bf2f((ushort)(vB.y & 0xffff)), wB, a2);
    a3 = fmaf(bf2f((ushort)(vB.y >> 16)), wB, a3);
    a0 = fmaf(bf2f((ushort)(vC.x & 0xffff)), wC, a0);
    a1 = fmaf(bf2f((ushort)(vC.x >> 16)), wC, a1);
    a2 = fmaf(bf2f((ushort)(vC.y & 0xffff)), wC, a2);
    a3 = fmaf(bf2f((ushort)(vC.y >> 16)), wC, a3);
    a0 = fmaf(bf2f((ushort)(vD.x & 0xffff)), wD, a0);
    a1 = fmaf(bf2f((ushort)(vD.x >> 16)), wD, a1);
    a2 = fmaf(bf2f((ushort)(vD.y & 0xffff)), wD, a2);
    a3 = fmaf(bf2f((ushort)(vD.y >> 16)), wD, a3);
  }
  a0 += __shfl_xor(a0, 4); a0 += __shfl_xor(a0, 8);
  a1 += __shfl_xor(a1, 4); a1 += __shfl_xor(a1, 8);
  a2 += __shfl_xor(a2, 4); a2 += __shfl_xor(a2, 8);
  a3 += __shfl_xor(a3, 4); a3 += __shfl_xor(a3, 8);
  uint2 sv = *(const uint2*)(h + (size_t)node * DIM_OUT + c * 4);
  float s2 = dd * dd;
  a0 = fmaf(bf2f((ushort)(sv.x & 0xffff)), s2, a0) + b[4 * c + 0];
  a1 = fmaf(bf2f((ushort)(sv.x >> 16)), s2, a1) + b[4 * c + 1];
  a2 = fmaf(bf2f((ushort)(sv.y & 0xffff)), s2, a2) + b[4 * c + 2];
  a3 = fmaf(bf2f((ushort)(sv.y >> 16)), s2, a3) + b[4 * c + 3];
  float m = fmaxf(fmaxf(a0, a1), fmaxf(a2, a3));
  m = fmaxf(m, __shfl_xor(m, 1));
  m = fmaxf(m, __shfl_xor(m, 2));
  float ssum = expf(a0 - m) + expf(a1 - m) + expf(a2 - m) + expf(a3 - m);
  ssum += __shfl_xor(ssum, 1);
  ssum += __shfl_xor(ssum, 2);
  float l = m + logf(ssum);
  if (e == 0)
    *(float4*)(out + (size_t)node * DIM_OUT + c * 4) =
        make_float4(a0 - l, a1 - l, a2 - l, a3 - l);
}

// ======================= launch =======================

extern "C" void kernel_launch(void* const* d_in, const int* in_sizes, int n_in,
                              void* d_out, int out_size, void* d_ws, size_t ws_size,
                              hipStream_t stream) {
  const float* x  = (const float*)d_in[0];
  const int*   ei = (const int*)d_in[1];
  const float* W1 = (const float*)d_in[2];
  const float* b1 = (const float*)d_in[3];
  const float* W2 = (const float*)d_in[4];
  const float* b2 = (const float*)d_in[5];
  float* out = (float*)d_out;

  const int n = in_sizes[0] / DIM_IN;  // 100000
  const int E = in_sizes[1] / 2;       // 1600000
  const int* srcv = ei;
  const int* dstv = ei + E;
  const int NB = (n + 255) >> NBSHIFT;  // 391
  const int NC = (E + CHUNK - 1) / CHUNK;  // 196 (<=256)

  char* wsb = (char*)d_ws;
  int* degi      = (int*)wsb;   wsb += (size_t)n * 4;
  int* rowptr    = (int*)wsb;   wsb += (size_t)n * 4;
  float* dinv    = (float*)wsb; wsb += (size_t)n * 4;
  int* gbhist    = (int*)wsb;   wsb += 512 * 4;
  int* bbase     = (int*)wsb;   wsb += 512 * 4;
  int* chunkhist = (int*)wsb;   wsb += (size_t)256 * 512 * 4;
  int* cstart    = (int*)wsb;   wsb += (size_t)256 * 512 * 4;
  int* srcs      = (int*)wsb;   wsb += (size_t)E * 4;
  ushort* wedge  = (ushort*)wsb; wsb += (size_t)E * 2;
  ushort* h1     = (ushort*)wsb; wsb += (size_t)n * DIM_H * 2;
  ushort* agg1   = (ushort*)wsb; wsb += (size_t)n * DIM_H * 2;
  ushort* h2     = (ushort*)wsb; wsb += (size_t)n * DIM_OUT * 2;
  // pairs (E uint = 6.4 MB) aliases agg1 (12.8 MB): dead before k_gather64 writes
  uint* pairs = (uint*)agg1;

  // ---- CSR build (deterministic, atomic-free) ----
  k_hist1<<<NC, 256, 0, stream>>>(dstv, E, chunkhist);
  k_scanc<<<512, 256, 0, stream>>>(chunkhist, NC, cstart, gbhist);
  k_bscan<<<1, 512, 0, stream>>>(gbhist, bbase);
  k_part2<<<NC, 256, 0, stream>>>(srcv, dstv, E, cstart, bbase, pairs);
  k_csr<<<NB, 256, 0, stream>>>(pairs, gbhist, bbase, n, degi, dinv, rowptr, srcs);
  k_wedge<<<(E + 255) / 256, 256, 0, stream>>>(srcs, dinv, wedge, E);

  // ---- layer 1 ----
  k_gemm1m<<<512, 256, 0, stream>>>(x, W1, h1, n, (n + 15) / 16);
  k_gather64<<<(n + 3) / 4, 256, 0, stream>>>(h1, srcs, wedge, rowptr, degi, dinv,
                                              b1, agg1, n);

  // ---- layer 2 ----
  k_gemm2<<<(n + 255) / 256, 256, 0, stream>>>(agg1, W2, h2, n);
  k_gather16<<<(n + 15) / 16, 256, 0, stream>>>(h2, srcs, wedge, rowptr, degi, dinv,
                                                b2, out, n);
}